// Round 19
// baseline (539.344 us; speedup 1.0000x reference)
//
#include <hip/hip_runtime.h>
#include <hip/hip_bf16.h>

#define Dd 1024
#define Hh 4096
#define Ee 8
#define Tt 4096   // tokens = 2*2048
#define Kk 2

typedef __attribute__((ext_vector_type(8))) short short8;
typedef __attribute__((ext_vector_type(4))) float f32x4;

__device__ __forceinline__ unsigned short f2bf_bits(float f) {
  unsigned u = __builtin_bit_cast(unsigned, f);
  u += 0x7FFFu + ((u >> 16) & 1u);   // RNE (finite values)
  return (unsigned short)(u >> 16);
}

__device__ __forceinline__ void glds16(const void* g, void* l) {
  __builtin_amdgcn_global_load_lds(
      (const __attribute__((address_space(1))) unsigned int*)g,
      (__attribute__((address_space(3))) unsigned int*)l, 16, 0, 0);
}

// ---------------- fused fp32 -> bf16 conversion for W1 and W2 (one launch) ----------------
__global__ __launch_bounds__(256) void cvt_both_kernel(
    const float* __restrict__ w1, unsigned short* __restrict__ w1b,
    const float* __restrict__ w2, unsigned short* __restrict__ w2b, int n4each) {
  int i = blockIdx.x * blockDim.x + threadIdx.x;
  int stride = gridDim.x * blockDim.x;
  for (; i < 2 * n4each; i += stride) {
    const float4* src = (i < n4each) ? reinterpret_cast<const float4*>(w1)
                                     : reinterpret_cast<const float4*>(w2);
    ushort4* dst = (i < n4each) ? reinterpret_cast<ushort4*>(w1b)
                                : reinterpret_cast<ushort4*>(w2b);
    int k = (i < n4each) ? i : i - n4each;
    float4 v = src[k];
    ushort4 o;
    o.x = f2bf_bits(v.x);
    o.y = f2bf_bits(v.y);
    o.z = f2bf_bits(v.z);
    o.w = f2bf_bits(v.w);
    dst[k] = o;
  }
}

// ---------------- router: softmax + top-2 + expert lists + fused token gather ----------------
__global__ __launch_bounds__(256) void router_kernel(
    const float* __restrict__ x, const float* __restrict__ Wr, const float* __restrict__ br,
    int* __restrict__ cnt, int* __restrict__ list, float* __restrict__ g2,
    unsigned short* __restrict__ xg) {
  int t = blockIdx.x * 4 + (threadIdx.x >> 6);
  int lane = threadIdx.x & 63;
  const float* xr = x + (size_t)t * Dd;
  float pe[Ee];
#pragma unroll
  for (int e = 0; e < Ee; e++) pe[e] = 0.f;
  for (int d = lane; d < Dd; d += 64) {
    float xv = xr[d];
#pragma unroll
    for (int e = 0; e < Ee; e++) pe[e] += xv * Wr[e * Dd + d];
  }
#pragma unroll
  for (int e = 0; e < Ee; e++) {
    float v = pe[e];
#pragma unroll
    for (int s = 32; s > 0; s >>= 1) v += __shfl_xor(v, s);
    pe[e] = v + br[e];
  }
  int e0 = 0, e1 = 0, p0 = 0, p1 = 0;
  if (lane == 0) {
    float mx = pe[0];
#pragma unroll
    for (int e = 1; e < Ee; e++) mx = fmaxf(mx, pe[e]);
    float g[Ee];
    float sum = 0.f;
#pragma unroll
    for (int e = 0; e < Ee; e++) { g[e] = expf(pe[e] - mx); sum += g[e]; }
    float inv = 1.0f / sum;
    float g0v = g[0];
#pragma unroll
    for (int e = 1; e < Ee; e++) if (g[e] > g0v) { g0v = g[e]; e0 = e; }
    float g1v = -1.f;
#pragma unroll
    for (int e = 0; e < Ee; e++) if (e != e0 && g[e] > g1v) { g1v = g[e]; e1 = e; }
    g2[t * 2 + 0] = g0v * inv;
    g2[t * 2 + 1] = g1v * inv;
    p0 = atomicAdd(&cnt[e0], 1);
    list[e0 * Tt + p0] = t * 2;
    p1 = atomicAdd(&cnt[e1], 1);
    list[e1 * Tt + p1] = t * 2 + 1;
  }
  e0 = __shfl(e0, 0); p0 = __shfl(p0, 0);
  e1 = __shfl(e1, 0); p1 = __shfl(p1, 0);
  ushort4* r0 = (ushort4*)(xg + ((size_t)e0 * Tt + p0) * Dd);
  ushort4* r1 = (ushort4*)(xg + ((size_t)e1 * Tt + p1) * Dd);
  const float4* x4 = reinterpret_cast<const float4*>(xr);
  for (int c = lane; c < Dd / 4; c += 64) {
    float4 v = x4[c];
    ushort4 o;
    o.x = f2bf_bits(v.x);
    o.y = f2bf_bits(v.y);
    o.z = f2bf_bits(v.z);
    o.w = f2bf_bits(v.w);
    r0[c] = o;
    r1[c] = o;
  }
}

// meta: [0..7]=row offs, [8..15]=ceil(ce/128) (gemm1), [16..23]=ceil(ce/256) (gemm2)
__global__ void scan_kernel(const int* __restrict__ cnt, int* __restrict__ meta) {
  if (threadIdx.x == 0 && blockIdx.x == 0) {
    int a = 0;
    for (int e = 0; e < Ee; e++) {
      meta[e] = a; a += cnt[e];
      meta[8 + e] = (cnt[e] + 127) >> 7;
      meta[16 + e] = (cnt[e] + 255) >> 8;
    }
  }
}

// ================== GEMM1: 128x128, BK=32, 4 waves — r12/r18-proven ==================
#define STAGE1(so_, k0)                                \
  do {                                                 \
    glds16(aS0 + (k0), AsW + (so_) * 4096);            \
    glds16(aS1 + (k0), AsW + (so_) * 4096 + 2048);     \
    glds16(bS0 + (k0), BsW + (so_) * 4096);            \
    glds16(bS1 + (k0), BsW + (so_) * 4096 + 2048);     \
  } while (0)

#define COMPUTE1(so_)                                                           \
  do {                                                                          \
    short8 af[4], bv[4];                                                        \
    _Pragma("unroll") for (int i = 0; i < 4; i++)                               \
        af[i] = *reinterpret_cast<const short8*>(                               \
            &As[(so_) * 4096 + (wm * 64 + i * 16 + fr) * 32 + gph]);            \
    _Pragma("unroll") for (int j = 0; j < 4; j++)                               \
        bv[j] = *reinterpret_cast<const short8*>(                               \
            &Bs[(so_) * 4096 + (wn * 64 + j * 16 + fr) * 32 + gph]);            \
    _Pragma("unroll") for (int i = 0; i < 4; i++)                               \
      _Pragma("unroll") for (int j = 0; j < 4; j++)                             \
          acc[i][j] = __builtin_amdgcn_mfma_f32_16x16x32_bf16(af[i], bv[j],     \
                                                              acc[i][j], 0, 0, 0); \
  } while (0)

#define PIPELINE1(NKT)                                             \
  do {                                                             \
    STAGE1(0, 0);                                                  \
    STAGE1(1, 32);                                                 \
    for (int kt = 0; kt <= (NKT)-3; ++kt) {                        \
      int so = kt & 1;                                             \
      asm volatile("s_waitcnt vmcnt(4)" ::: "memory");             \
      __builtin_amdgcn_s_barrier();                                \
      COMPUTE1(so);                                                \
      __builtin_amdgcn_s_barrier();                                \
      STAGE1(so, (kt + 2) * 32);                                   \
    }                                                              \
    asm volatile("s_waitcnt vmcnt(4)" ::: "memory");               \
    __builtin_amdgcn_s_barrier();                                  \
    COMPUTE1(((NKT)-2) & 1);                                       \
    asm volatile("s_waitcnt vmcnt(0)" ::: "memory");               \
    __builtin_amdgcn_s_barrier();                                  \
    COMPUTE1(((NKT)-1) & 1);                                       \
  } while (0)

__global__ __launch_bounds__(256) void gemm1_kernel(
    const unsigned short* __restrict__ xg, const unsigned short* __restrict__ w1b,
    const float* __restrict__ b1,
    const int* __restrict__ cnt, const int* __restrict__ meta,
    unsigned short* __restrict__ hb) {
  int e = blockIdx.x & 7;
  int G = gridDim.x >> 3;
  int m_e = meta[8 + e];
  int ce = cnt[e], off_e = meta[e];
  int span = m_e * (Hh / 128);

  __shared__ short As[2 * 4096];
  __shared__ short Bs[2 * 4096];

  int tid = threadIdx.x;
  int lane = tid & 63;
  int w = tid >> 6;
  int wm = w >> 1, wn = w & 1;
  int fr = lane & 15, kq = lane >> 4;

  int r0 = tid >> 2;
  int swz = ((tid & 3) ^ ((r0 >> 1) & 3)) << 3;
  short* AsW = &As[w * 512];
  short* BsW = &Bs[w * 512];
  int gph = (kq ^ ((fr >> 1) & 3)) << 3;
  const float* b1e = b1 + (size_t)e * Hh;

  for (int local = blockIdx.x >> 3; local < span; local += G) {
    int nt = local / m_e, mt = local % m_e;
    __syncthreads();

    const unsigned short* aS0 = xg + (size_t)e * Tt * Dd + (size_t)(mt * 128 + r0) * Dd + swz;
    const unsigned short* aS1 = aS0 + (size_t)64 * Dd;
    const unsigned short* bS0 = w1b + (size_t)e * Hh * Dd + (size_t)(nt * 128 + r0) * Dd + swz;
    const unsigned short* bS1 = bS0 + (size_t)64 * Dd;

    float biasj[4];
#pragma unroll
    for (int j = 0; j < 4; j++) biasj[j] = b1e[nt * 128 + wn * 64 + j * 16 + fr];
    asm volatile("s_waitcnt vmcnt(0)" ::: "memory");

    f32x4 acc[4][4] = {};
    PIPELINE1(Dd / 32);

#pragma unroll
    for (int i = 0; i < 4; i++) {
      int rb = wm * 64 + i * 16 + kq * 4;
#pragma unroll
      for (int j = 0; j < 4; j++) {
        int col = nt * 128 + wn * 64 + j * 16 + fr;
#pragma unroll
        for (int rr = 0; rr < 4; rr++) {
          int grow = mt * 128 + rb + rr;
          if (grow < ce) {
            float v = acc[i][j][rr] + biasj[j];
            v = 0.5f * v * (1.0f + erff(v * 0.70710678118654752f));
            hb[(size_t)(off_e + grow) * Hh + col] = f2bf_bits(v);
          }
        }
      }
    }
  }
}

// ====== GEMM2: 256x256, BK=32, 8 waves, 4-slot depth-3 counted pipeline (NEW) ======
// LDS: 4 slots x [256 rows][32 shorts] per operand = 64 KB each, A+B = 128 KB.
// Per K-tile/thread: 4 glds (2 A + 2 B). Depth-3: prologue stages tiles 0,1,2; at tile
// kt wait vmcnt(8) (tiles kt+1,kt+2 in flight; kt landed) -> ~2 tiles (>900cy) cover.
// ONE barrier per K-tile: a wave staging slot (kt+3)&3 at tile kt passed barrier kt,
// which all waves reach only after COMPUTE(kt-1) (reader of that slot) retired its
// ds_reads (waited before MFMA use). Swizzle = r12's 0-conflict scheme (row key
// (row>>1)&3 == (fr>>1)&3 for all read rows at this geometry).
#define STAGE2(sl, kt)                                             \
  do {                                                             \
    int k0_ = (kt) * 32;                                           \
    glds16(aS0 + k0_, AsW2 + (sl) * 8192);                         \
    glds16(aS1 + k0_, AsW2 + (sl) * 8192 + 4096);                  \
    glds16(bS0 + k0_, BsW2 + (sl) * 8192);                         \
    glds16(bS1 + k0_, BsW2 + (sl) * 8192 + 4096);                  \
  } while (0)

#define COMPUTE2(sl)                                                            \
  do {                                                                          \
    short8 af[8], bv[4];                                                        \
    _Pragma("unroll") for (int i = 0; i < 8; i++)                               \
        af[i] = *reinterpret_cast<const short8*>(                               \
            &As[(sl) * 8192 + (wm * 128 + i * 16 + fr) * 32 + gph]);            \
    _Pragma("unroll") for (int j = 0; j < 4; j++)                               \
        bv[j] = *reinterpret_cast<const short8*>(                               \
            &Bs[(sl) * 8192 + (wn * 64 + j * 16 + fr) * 32 + gph]);             \
    _Pragma("unroll") for (int i = 0; i < 8; i++)                               \
      _Pragma("unroll") for (int j = 0; j < 4; j++)                             \
          acc[i][j] = __builtin_amdgcn_mfma_f32_16x16x32_bf16(af[i], bv[j],     \
                                                              acc[i][j], 0, 0, 0); \
  } while (0)

__global__ __launch_bounds__(512, 1) void gemm2_kernel(
    const unsigned short* __restrict__ hb, const unsigned short* __restrict__ w2b,
    const float* __restrict__ b2,
    const int* __restrict__ cnt, const int* __restrict__ meta, const int* __restrict__ list,
    float* __restrict__ yb) {
  int e = blockIdx.x & 7;
  int G = gridDim.x >> 3;
  int m_e = meta[16 + e];          // ceil(ce/256)
  int ce = cnt[e], off_e = meta[e];
  int span = m_e * (Dd / 256) * 2; // 4 nt x 2 ks

  __shared__ short As[4 * 8192];
  __shared__ short Bs[4 * 8192];

  int tid = threadIdx.x;
  int lane = tid & 63;
  int w = tid >> 6;                // 0..7
  int wm = w >> 2, wn = w & 3;     // 2M x 4N
  int fr = lane & 15, kq = lane >> 4;

  int r0 = tid >> 2;                               // staging row 0..127 (+128 second sweep)
  int swz = ((tid & 3) ^ ((r0 >> 1) & 3)) << 3;    // source granule pre-swizzle
  short* AsW2 = &As[w * 512];
  short* BsW2 = &Bs[w * 512];
  int gph = (kq ^ ((fr >> 1) & 3)) << 3;
  const int* le = list + e * Tt;
  const float* b2e = b2 + (size_t)e * Dd;

  for (int local = blockIdx.x >> 3; local < span; local += G) {
    int g = local / m_e, mt = local % m_e;   // mt-inner within each (nt,ks) group
    int nt = g >> 1, ks = g & 1;
    __syncthreads();

    // hb padded +256 rows: no clamps (overrun A-rows are garbage M-rows, outputs guarded)
    const unsigned short* aS0 = hb + (size_t)(off_e + mt * 256 + r0) * Hh + ks * 2048 + swz;
    const unsigned short* aS1 = aS0 + (size_t)128 * Hh;
    const unsigned short* bS0 = w2b + (size_t)e * Dd * Hh + (size_t)(nt * 256 + r0) * Hh + ks * 2048 + swz;
    const unsigned short* bS1 = bS0 + (size_t)128 * Hh;

    float bsc = (ks == 0) ? 1.f : 0.f;
    float biasj[4];
#pragma unroll
    for (int j = 0; j < 4; j++)
      biasj[j] = b2e[nt * 256 + wn * 64 + j * 16 + fr] * bsc;
    asm volatile("s_waitcnt vmcnt(0)" ::: "memory");

    f32x4 acc[8][4] = {};
    const int NKT = 2048 / 32;   // 64 K-tiles per split
    STAGE2(0, 0);
    STAGE2(1, 1);
    STAGE2(2, 2);
    for (int kt = 0; kt < NKT; ++kt) {
      if (kt <= NKT - 3)
        asm volatile("s_waitcnt vmcnt(8)" ::: "memory");
      else if (kt == NKT - 2)
        asm volatile("s_waitcnt vmcnt(4)" ::: "memory");
      else
        asm volatile("s_waitcnt vmcnt(0)" ::: "memory");
      asm volatile("s_waitcnt lgkmcnt(0)" ::: "memory");
      __builtin_amdgcn_s_barrier();
      if (kt + 3 < NKT) STAGE2((kt + 3) & 3, kt + 3);
      COMPUTE2(kt & 3);
    }

    float* yk = yb + (size_t)ks * Tt * Kk * Dd;
#pragma unroll
    for (int i = 0; i < 8; i++) {
      int rb = wm * 128 + i * 16 + kq * 4;
#pragma unroll
      for (int j = 0; j < 4; j++) {
        int col = nt * 256 + wn * 64 + j * 16 + fr;
#pragma unroll
        for (int rr = 0; rr < 4; rr++) {
          int grow = mt * 256 + rb + rr;
          if (grow < ce) {
            int en = le[grow];
            yk[(size_t)en * Dd + col] = acc[i][j][rr] + biasj[j];
          }
        }
      }
    }
  }
}

// ---------------- combine: out[t] = g0*(y0[2t]+y1[2t]) + g1*(y0[2t+1]+y1[2t+1]) --------
__global__ __launch_bounds__(256) void combine_kernel(
    const float* __restrict__ yb, const float* __restrict__ g2, float* __restrict__ out) {
  const int C4 = Dd / 4;
  const size_t HALF = (size_t)Tt * Kk * Dd / 4;   // in float4 units
  int i = blockIdx.x * blockDim.x + threadIdx.x;
  int t = i / C4;
  int c = i % C4;
  float g0 = g2[t * 2 + 0];
  float g1 = g2[t * 2 + 1];
  const float4* y4 = reinterpret_cast<const float4*>(yb);
  float4 a0 = y4[(size_t)(t * 2 + 0) * C4 + c];
  float4 a1 = y4[HALF + (size_t)(t * 2 + 0) * C4 + c];
  float4 b0 = y4[(size_t)(t * 2 + 1) * C4 + c];
  float4 b1v = y4[HALF + (size_t)(t * 2 + 1) * C4 + c];
  float4 o;
  o.x = g0 * (a0.x + a1.x) + g1 * (b0.x + b1v.x);
  o.y = g0 * (a0.y + a1.y) + g1 * (b0.y + b1v.y);
  o.z = g0 * (a0.z + a1.z) + g1 * (b0.z + b1v.z);
  o.w = g0 * (a0.w + a1.w) + g1 * (b0.w + b1v.w);
  reinterpret_cast<float4*>(out)[i] = o;
}

extern "C" void kernel_launch(void* const* d_in, const int* in_sizes, int n_in,
                              void* d_out, int out_size, void* d_ws, size_t ws_size,
                              hipStream_t stream) {
  const float* x  = (const float*)d_in[0];
  const float* Wr = (const float*)d_in[1];
  const float* br = (const float*)d_in[2];
  const float* W1 = (const float*)d_in[3];
  const float* b1 = (const float*)d_in[4];
  const float* W2 = (const float*)d_in[5];
  const float* b2 = (const float*)d_in[6];
  float* out = (float*)d_out;

  char* base = (char*)d_ws;
  size_t o = 0;
  auto alloc = [&](size_t n) { char* r = base + o; o += (n + 255) & ~(size_t)255; return r; };
  unsigned short* w1b = (unsigned short*)alloc((size_t)Ee * Hh * Dd * 2);
  unsigned short* w2b = (unsigned short*)alloc((size_t)Ee * Dd * Hh * 2);
  unsigned short* xg  = (unsigned short*)alloc((size_t)Ee * Tt * Dd * 2);
  unsigned short* hb  = (unsigned short*)alloc((size_t)(Tt * Kk + 256) * Hh * 2);
  int* list  = (int*)alloc((size_t)Ee * Tt * 4);
  float* g2  = (float*)alloc((size_t)Tt * Kk * 4);
  int* cnt   = (int*)alloc(Ee * 4);
  int* meta  = (int*)alloc(32 * 4);
  if (o > ws_size) return;  // workspace too small: fail loudly (output stays poisoned)

  // xg (64MB) dead after gemm1; holds yb[2][Tt*Kk][Dd] f32 (2 x 32MB).
  float* yb = (float*)xg;

  hipMemsetAsync(cnt, 0, Ee * 4, stream);

  cvt_both_kernel<<<8192, 256, 0, stream>>>(W1, w1b, W2, w2b, Ee * Hh * Dd / 4);
  router_kernel<<<Tt / 4, 256, 0, stream>>>(x, Wr, br, cnt, list, g2, xg);
  scan_kernel<<<1, 64, 0, stream>>>(cnt, meta);

  gemm1_kernel<<<2048, 256, 0, stream>>>(xg, w1b, b1, cnt, meta, hb);
  gemm2_kernel<<<256, 512, 0, stream>>>(hb, w2b, b2, cnt, meta, list, yb);
  combine_kernel<<<(Tt * Dd / 4) / 256, 256, 0, stream>>>(yb, g2, out);
}

// Round 20
// 490.921 us; speedup vs baseline: 1.0986x; 1.0986x over previous
//
#include <hip/hip_runtime.h>
#include <hip/hip_bf16.h>

#define Dd 1024
#define Hh 4096
#define Ee 8
#define Tt 4096   // tokens = 2*2048
#define Kk 2

typedef __attribute__((ext_vector_type(8))) short short8;
typedef __attribute__((ext_vector_type(4))) float f32x4;

__device__ __forceinline__ unsigned short f2bf_bits(float f) {
  unsigned u = __builtin_bit_cast(unsigned, f);
  u += 0x7FFFu + ((u >> 16) & 1u);   // RNE (finite values)
  return (unsigned short)(u >> 16);
}

__device__ __forceinline__ void glds16(const void* g, void* l) {
  __builtin_amdgcn_global_load_lds(
      (const __attribute__((address_space(1))) unsigned int*)g,
      (__attribute__((address_space(3))) unsigned int*)l, 16, 0, 0);
}

// ======= fused: router (blocks 0..1023) + W1/W2 fp32->bf16 convert (rest) =======
__global__ __launch_bounds__(256) void cvt_router_kernel(
    const float* __restrict__ x, const float* __restrict__ Wr, const float* __restrict__ br,
    const float* __restrict__ w1, unsigned short* __restrict__ w1b,
    const float* __restrict__ w2, unsigned short* __restrict__ w2b,
    int* __restrict__ cnt, int* __restrict__ list, float* __restrict__ g2,
    unsigned short* __restrict__ xg) {
  const int RB = Tt / 4;   // 1024 router blocks
  if (blockIdx.x < RB) {
    // ---- router: softmax + top-2 + expert lists + fused token gather ----
    int t = blockIdx.x * 4 + (threadIdx.x >> 6);
    int lane = threadIdx.x & 63;
    const float* xr = x + (size_t)t * Dd;
    float pe[Ee];
#pragma unroll
    for (int e = 0; e < Ee; e++) pe[e] = 0.f;
    for (int d = lane; d < Dd; d += 64) {
      float xv = xr[d];
#pragma unroll
      for (int e = 0; e < Ee; e++) pe[e] += xv * Wr[e * Dd + d];
    }
#pragma unroll
    for (int e = 0; e < Ee; e++) {
      float v = pe[e];
#pragma unroll
      for (int s = 32; s > 0; s >>= 1) v += __shfl_xor(v, s);
      pe[e] = v + br[e];
    }
    int e0 = 0, e1 = 0, p0 = 0, p1 = 0;
    if (lane == 0) {
      float mx = pe[0];
#pragma unroll
      for (int e = 1; e < Ee; e++) mx = fmaxf(mx, pe[e]);
      float g[Ee];
      float sum = 0.f;
#pragma unroll
      for (int e = 0; e < Ee; e++) { g[e] = expf(pe[e] - mx); sum += g[e]; }
      float inv = 1.0f / sum;
      float g0v = g[0];
#pragma unroll
      for (int e = 1; e < Ee; e++) if (g[e] > g0v) { g0v = g[e]; e0 = e; }
      float g1v = -1.f;
#pragma unroll
      for (int e = 0; e < Ee; e++) if (e != e0 && g[e] > g1v) { g1v = g[e]; e1 = e; }
      g2[t * 2 + 0] = g0v * inv;
      g2[t * 2 + 1] = g1v * inv;
      p0 = atomicAdd(&cnt[e0], 1);
      list[e0 * Tt + p0] = t * 2;
      p1 = atomicAdd(&cnt[e1], 1);
      list[e1 * Tt + p1] = t * 2 + 1;
    }
    e0 = __shfl(e0, 0); p0 = __shfl(p0, 0);
    e1 = __shfl(e1, 0); p1 = __shfl(p1, 0);
    ushort4* r0 = (ushort4*)(xg + ((size_t)e0 * Tt + p0) * Dd);
    ushort4* r1 = (ushort4*)(xg + ((size_t)e1 * Tt + p1) * Dd);
    const float4* x4 = reinterpret_cast<const float4*>(xr);
    for (int c = lane; c < Dd / 4; c += 64) {
      float4 v = x4[c];
      ushort4 o;
      o.x = f2bf_bits(v.x);
      o.y = f2bf_bits(v.y);
      o.z = f2bf_bits(v.z);
      o.w = f2bf_bits(v.w);
      r0[c] = o;
      r1[c] = o;
    }
  } else {
    // ---- weight conversion (grid-stride over W1 then W2, float4 granularity) ----
    const int n4each = Ee * Hh * Dd / 4;
    int i = (blockIdx.x - RB) * 256 + threadIdx.x;
    int stride = (gridDim.x - RB) * 256;
    for (; i < 2 * n4each; i += stride) {
      const float4* src = (i < n4each) ? reinterpret_cast<const float4*>(w1)
                                       : reinterpret_cast<const float4*>(w2);
      ushort4* dst = (i < n4each) ? reinterpret_cast<ushort4*>(w1b)
                                  : reinterpret_cast<ushort4*>(w2b);
      int k = (i < n4each) ? i : i - n4each;
      float4 v = src[k];
      ushort4 o;
      o.x = f2bf_bits(v.x);
      o.y = f2bf_bits(v.y);
      o.z = f2bf_bits(v.z);
      o.w = f2bf_bits(v.w);
      dst[k] = o;
    }
  }
}

// ================== 128x128 tile, BK=32, 4 waves (2x2) — r12/r14/r18-proven ==============
// 2-buffer counted pipeline (vmcnt(4), one tile in flight); LDS [row(128)][32] 64B rows,
// staging 4 lanes/row (fully-used lines); granule swizzle both sides -> 0 conflicts (HW).
#define STAGE(so_, k0)                                 \
  do {                                                 \
    glds16(aS0 + (k0), AsW + (so_) * 4096);            \
    glds16(aS1 + (k0), AsW + (so_) * 4096 + 2048);     \
    glds16(bS0 + (k0), BsW + (so_) * 4096);            \
    glds16(bS1 + (k0), BsW + (so_) * 4096 + 2048);     \
  } while (0)

#define COMPUTE(so_)                                                            \
  do {                                                                          \
    short8 af[4], bv[4];                                                        \
    _Pragma("unroll") for (int i = 0; i < 4; i++)                               \
        af[i] = *reinterpret_cast<const short8*>(                               \
            &As[(so_) * 4096 + (wm * 64 + i * 16 + fr) * 32 + gph]);            \
    _Pragma("unroll") for (int j = 0; j < 4; j++)                               \
        bv[j] = *reinterpret_cast<const short8*>(                               \
            &Bs[(so_) * 4096 + (wn * 64 + j * 16 + fr) * 32 + gph]);            \
    _Pragma("unroll") for (int i = 0; i < 4; i++)                               \
      _Pragma("unroll") for (int j = 0; j < 4; j++)                             \
          acc[i][j] = __builtin_amdgcn_mfma_f32_16x16x32_bf16(af[i], bv[j],     \
                                                              acc[i][j], 0, 0, 0); \
  } while (0)

#define PIPELINE(NKT)                                              \
  do {                                                             \
    STAGE(0, 0);                                                   \
    STAGE(1, 32);                                                  \
    for (int kt = 0; kt <= (NKT)-3; ++kt) {                        \
      int so = kt & 1;                                             \
      asm volatile("s_waitcnt vmcnt(4)" ::: "memory");             \
      __builtin_amdgcn_s_barrier();                                \
      COMPUTE(so);                                                 \
      __builtin_amdgcn_s_barrier();                                \
      STAGE(so, (kt + 2) * 32);                                    \
    }                                                              \
    asm volatile("s_waitcnt vmcnt(4)" ::: "memory");               \
    __builtin_amdgcn_s_barrier();                                  \
    COMPUTE(((NKT)-2) & 1);                                        \
    asm volatile("s_waitcnt vmcnt(0)" ::: "memory");               \
    __builtin_amdgcn_s_barrier();                                  \
    COMPUTE(((NKT)-1) & 1);                                        \
  } while (0)

// Inline per-block meta from cnt (replaces scan_kernel): off_e = prefix, m_e = ceil(ce/128)
#define EXPERT_META                                    \
  int ce = cnt[e];                                     \
  int off_e = 0;                                       \
  _Pragma("unroll") for (int i_ = 0; i_ < Ee; i_++)    \
      off_e += (i_ < e) ? cnt[i_] : 0;                 \
  int m_e = (ce + 127) >> 7;

// ---------------- GEMM1 (r18): h = gelu(xg @ W1[e]^T + b1[e]) -> bf16 ------------------
__global__ __launch_bounds__(256) void gemm1_kernel(
    const unsigned short* __restrict__ xg, const unsigned short* __restrict__ w1b,
    const float* __restrict__ b1,
    const int* __restrict__ cnt,
    unsigned short* __restrict__ hb) {
  int e = blockIdx.x & 7;
  int G = gridDim.x >> 3;
  EXPERT_META
  int span = m_e * (Hh / 128);

  __shared__ short As[2 * 4096];
  __shared__ short Bs[2 * 4096];

  int tid = threadIdx.x;
  int lane = tid & 63;
  int w = tid >> 6;
  int wm = w >> 1, wn = w & 1;
  int fr = lane & 15, kq = lane >> 4;

  int r0 = tid >> 2;
  int swz = ((tid & 3) ^ ((r0 >> 1) & 3)) << 3;
  short* AsW = &As[w * 512];
  short* BsW = &Bs[w * 512];
  int gph = (kq ^ ((fr >> 1) & 3)) << 3;
  const float* b1e = b1 + (size_t)e * Hh;

  for (int local = blockIdx.x >> 3; local < span; local += G) {
    int nt = local / m_e, mt = local % m_e;
    __syncthreads();

    const unsigned short* aS0 = xg + (size_t)e * Tt * Dd + (size_t)(mt * 128 + r0) * Dd + swz;
    const unsigned short* aS1 = aS0 + (size_t)64 * Dd;
    const unsigned short* bS0 = w1b + (size_t)e * Hh * Dd + (size_t)(nt * 128 + r0) * Dd + swz;
    const unsigned short* bS1 = bS0 + (size_t)64 * Dd;

    float biasj[4];
#pragma unroll
    for (int j = 0; j < 4; j++) biasj[j] = b1e[nt * 128 + wn * 64 + j * 16 + fr];
    asm volatile("s_waitcnt vmcnt(0)" ::: "memory");

    f32x4 acc[4][4] = {};
    PIPELINE(Dd / 32);

#pragma unroll
    for (int i = 0; i < 4; i++) {
      int rb = wm * 64 + i * 16 + kq * 4;
#pragma unroll
      for (int j = 0; j < 4; j++) {
        int col = nt * 128 + wn * 64 + j * 16 + fr;
#pragma unroll
        for (int rr = 0; rr < 4; rr++) {
          int grow = mt * 128 + rb + rr;
          if (grow < ce) {
            float v = acc[i][j][rr] + biasj[j];
            v = 0.5f * v * (1.0f + erff(v * 0.70710678118654752f));
            hb[(size_t)(off_e + grow) * Hh + col] = f2bf_bits(v);
          }
        }
      }
    }
  }
}

// ---------------- GEMM2 (r18, best measured 174us): y[en] = h @ W2[e]^T + b2[e] --------
__global__ __launch_bounds__(256) void gemm2_kernel(
    const unsigned short* __restrict__ hb, const unsigned short* __restrict__ w2b,
    const float* __restrict__ b2,
    const int* __restrict__ cnt, const int* __restrict__ list,
    float* __restrict__ y) {
  int e = blockIdx.x & 7;
  int G = gridDim.x >> 3;
  EXPERT_META
  int span = m_e * (Dd / 128);

  __shared__ short As[2 * 4096];
  __shared__ short Bs[2 * 4096];

  int tid = threadIdx.x;
  int lane = tid & 63;
  int w = tid >> 6;
  int wm = w >> 1, wn = w & 1;
  int fr = lane & 15, kq = lane >> 4;

  int r0 = tid >> 2;
  int swz = ((tid & 3) ^ ((r0 >> 1) & 3)) << 3;
  short* AsW = &As[w * 512];
  short* BsW = &Bs[w * 512];
  int gph = (kq ^ ((fr >> 1) & 3)) << 3;
  const int* le = list + e * Tt;
  const float* b2e = b2 + (size_t)e * Dd;

  for (int local = blockIdx.x >> 3; local < span; local += G) {
    int nt = local / m_e, mt = local % m_e;
    __syncthreads();

    int ra0 = mt * 128 + r0;      if (ra0 >= ce) ra0 = ce - 1;
    int ra1 = mt * 128 + r0 + 64; if (ra1 >= ce) ra1 = ce - 1;
    const unsigned short* aS0 = hb + (size_t)(off_e + ra0) * Hh + swz;
    const unsigned short* aS1 = hb + (size_t)(off_e + ra1) * Hh + swz;
    const unsigned short* bS0 = w2b + (size_t)e * Dd * Hh + (size_t)(nt * 128 + r0) * Hh + swz;
    const unsigned short* bS1 = bS0 + (size_t)64 * Hh;

    float biasj[4];
#pragma unroll
    for (int j = 0; j < 4; j++) biasj[j] = b2e[nt * 128 + wn * 64 + j * 16 + fr];
    asm volatile("s_waitcnt vmcnt(0)" ::: "memory");

    f32x4 acc[4][4] = {};
    PIPELINE(Hh / 32);   // full K = 4096, 128 steps

#pragma unroll
    for (int i = 0; i < 4; i++) {
      int rb = wm * 64 + i * 16 + kq * 4;
#pragma unroll
      for (int j = 0; j < 4; j++) {
        int col = nt * 128 + wn * 64 + j * 16 + fr;
#pragma unroll
        for (int rr = 0; rr < 4; rr++) {
          int grow = mt * 128 + rb + rr;
          if (grow < ce) {
            int en = le[grow];
            y[(size_t)en * Dd + col] = acc[i][j][rr] + biasj[j];
          }
        }
      }
    }
  }
}

// ---------------- combine: out[t] = g0*y[2t] + g1*y[2t+1] ----------------
__global__ __launch_bounds__(256) void combine_kernel(
    const float* __restrict__ y, const float* __restrict__ g2, float* __restrict__ out) {
  const int C4 = Dd / 4;
  int i = blockIdx.x * blockDim.x + threadIdx.x;
  int t = i / C4;
  int c = i % C4;
  float g0 = g2[t * 2 + 0];
  float g1 = g2[t * 2 + 1];
  float4 y0 = reinterpret_cast<const float4*>(y)[(size_t)(t * 2 + 0) * C4 + c];
  float4 y1 = reinterpret_cast<const float4*>(y)[(size_t)(t * 2 + 1) * C4 + c];
  float4 o;
  o.x = g0 * y0.x + g1 * y1.x;
  o.y = g0 * y0.y + g1 * y1.y;
  o.z = g0 * y0.z + g1 * y1.z;
  o.w = g0 * y0.w + g1 * y1.w;
  reinterpret_cast<float4*>(out)[i] = o;
}

extern "C" void kernel_launch(void* const* d_in, const int* in_sizes, int n_in,
                              void* d_out, int out_size, void* d_ws, size_t ws_size,
                              hipStream_t stream) {
  const float* x  = (const float*)d_in[0];
  const float* Wr = (const float*)d_in[1];
  const float* br = (const float*)d_in[2];
  const float* W1 = (const float*)d_in[3];
  const float* b1 = (const float*)d_in[4];
  const float* W2 = (const float*)d_in[5];
  const float* b2 = (const float*)d_in[6];
  float* out = (float*)d_out;

  char* base = (char*)d_ws;
  size_t o = 0;
  auto alloc = [&](size_t n) { char* r = base + o; o += (n + 255) & ~(size_t)255; return r; };
  unsigned short* w1b = (unsigned short*)alloc((size_t)Ee * Hh * Dd * 2);
  unsigned short* w2b = (unsigned short*)alloc((size_t)Ee * Dd * Hh * 2);
  unsigned short* xg  = (unsigned short*)alloc((size_t)Ee * Tt * Dd * 2);
  unsigned short* hb  = (unsigned short*)alloc((size_t)(Tt * Kk + 256) * Hh * 2);
  int* list  = (int*)alloc((size_t)Ee * Tt * 4);
  float* g2  = (float*)alloc((size_t)Tt * Kk * 4);
  int* cnt   = (int*)alloc(Ee * 4);
  if (o > ws_size) return;  // workspace too small: fail loudly (output stays poisoned)

  // w1b (64MB) dead after gemm1; holds y[Tt*Kk][Dd] f32 (32MB).
  float* y = (float*)w1b;

  hipMemsetAsync(cnt, 0, Ee * 4, stream);

  cvt_router_kernel<<<1024 + 8192, 256, 0, stream>>>(x, Wr, br, W1, w1b, W2, w2b,
                                                     cnt, list, g2, xg);
  gemm1_kernel<<<2048, 256, 0, stream>>>(xg, w1b, b1, cnt, hb);
  gemm2_kernel<<<1024, 256, 0, stream>>>(hb, w2b, b2, cnt, list, y);
  combine_kernel<<<(Tt * Dd / 4) / 256, 256, 0, stream>>>(y, g2, out);
}

// Round 21
// 405.334 us; speedup vs baseline: 1.3306x; 1.2112x over previous
//
#include <hip/hip_runtime.h>
#include <hip/hip_bf16.h>

#define Dd 1024
#define Hh 4096
#define Ee 8
#define Tt 4096   // tokens = 2*2048
#define Kk 2

typedef __attribute__((ext_vector_type(8))) short short8;
typedef __attribute__((ext_vector_type(4))) float f32x4;

__device__ __forceinline__ unsigned short f2bf_bits(float f) {
  unsigned u = __builtin_bit_cast(unsigned, f);
  u += 0x7FFFu + ((u >> 16) & 1u);   // RNE (finite values)
  return (unsigned short)(u >> 16);
}

__device__ __forceinline__ unsigned pack2bf(float lo, float hi) {
  return (unsigned)f2bf_bits(lo) | ((unsigned)f2bf_bits(hi) << 16);
}

__device__ __forceinline__ void glds16(const void* g, void* l) {
  __builtin_amdgcn_global_load_lds(
      (const __attribute__((address_space(1))) unsigned int*)g,
      (__attribute__((address_space(3))) unsigned int*)l, 16, 0, 0);
}

// ---------------- W1/W2 fp32 -> bf16 (16B stores) ----------------
__global__ __launch_bounds__(256) void cvt_both_kernel(
    const float* __restrict__ w1, unsigned short* __restrict__ w1b,
    const float* __restrict__ w2, unsigned short* __restrict__ w2b, int n8each) {
  int i = blockIdx.x * blockDim.x + threadIdx.x;
  int stride = gridDim.x * blockDim.x;
  for (; i < 2 * n8each; i += stride) {
    const float4* src = (i < n8each) ? reinterpret_cast<const float4*>(w1)
                                     : reinterpret_cast<const float4*>(w2);
    uint4* dst = (i < n8each) ? reinterpret_cast<uint4*>(w1b)
                              : reinterpret_cast<uint4*>(w2b);
    int k = (i < n8each) ? i : i - n8each;
    float4 a = src[2 * k], b = src[2 * k + 1];
    uint4 o;
    o.x = pack2bf(a.x, a.y);
    o.y = pack2bf(a.z, a.w);
    o.z = pack2bf(b.x, b.y);
    o.w = pack2bf(b.z, b.w);
    dst[k] = o;
  }
}

// ---------------- router compute: top-2 experts + gates, NO atomics ----------------
__global__ __launch_bounds__(256) void router_kernel(
    const float* __restrict__ x, const float* __restrict__ Wr, const float* __restrict__ br,
    int* __restrict__ tokinfo, float* __restrict__ g2) {
  int t = blockIdx.x * 4 + (threadIdx.x >> 6);
  int lane = threadIdx.x & 63;
  const float4* x4 = reinterpret_cast<const float4*>(x + (size_t)t * Dd);
  const float4* Wr4 = reinterpret_cast<const float4*>(Wr);
  float pe[Ee];
#pragma unroll
  for (int e = 0; e < Ee; e++) pe[e] = 0.f;
  for (int c = lane; c < Dd / 4; c += 64) {
    float4 xv = x4[c];
#pragma unroll
    for (int e = 0; e < Ee; e++) {
      float4 wv = Wr4[e * (Dd / 4) + c];
      pe[e] += xv.x * wv.x + xv.y * wv.y + xv.z * wv.z + xv.w * wv.w;
    }
  }
#pragma unroll
  for (int e = 0; e < Ee; e++) {
    float v = pe[e];
#pragma unroll
    for (int s = 32; s > 0; s >>= 1) v += __shfl_xor(v, s);
    pe[e] = v + br[e];
  }
  if (lane == 0) {
    float mx = pe[0];
#pragma unroll
    for (int e = 1; e < Ee; e++) mx = fmaxf(mx, pe[e]);
    float g[Ee];
    float sum = 0.f;
#pragma unroll
    for (int e = 0; e < Ee; e++) { g[e] = expf(pe[e] - mx); sum += g[e]; }
    float inv = 1.0f / sum;
    int e0 = 0; float g0v = g[0];
#pragma unroll
    for (int e = 1; e < Ee; e++) if (g[e] > g0v) { g0v = g[e]; e0 = e; }
    int e1 = -1; float g1v = -1.f;
#pragma unroll
    for (int e = 0; e < Ee; e++) if (e != e0 && g[e] > g1v) { g1v = g[e]; e1 = e; }
    g2[t * 2 + 0] = g0v * inv;
    g2[t * 2 + 1] = g1v * inv;
    tokinfo[t] = e0 | (e1 << 8);
  }
}

// ---------------- assign: LDS counters -> list, pos, cnt (1 block) ----------------
__global__ void assign_kernel(const int* __restrict__ tokinfo, int* __restrict__ pos,
                              int* __restrict__ list, int* __restrict__ cnt) {
  __shared__ int lc[Ee];
  int tid = threadIdx.x;
  if (tid < Ee) lc[tid] = 0;
  __syncthreads();
  for (int t = tid; t < Tt; t += 256) {
    int info = tokinfo[t];
    int e0 = info & 255, e1 = info >> 8;
    int p0 = atomicAdd(&lc[e0], 1);
    list[e0 * Tt + p0] = t * 2;
    pos[t * 2] = (e0 << 16) | p0;
    int p1 = atomicAdd(&lc[e1], 1);
    list[e1 * Tt + p1] = t * 2 + 1;
    pos[t * 2 + 1] = (e1 << 16) | p1;
  }
  __syncthreads();
  if (tid < Ee) cnt[tid] = lc[tid];
}

// ---------------- gather: x rows -> xg (bf16, contiguous per expert; 16B stores) -------
__global__ __launch_bounds__(256) void gather_kernel(
    const float* __restrict__ x, const int* __restrict__ pos,
    unsigned short* __restrict__ xg) {
  int t = blockIdx.x * 4 + (threadIdx.x >> 6);
  int lane = threadIdx.x & 63;
  int pk0 = pos[t * 2], pk1 = pos[t * 2 + 1];
  uint4* r0 = (uint4*)(xg + ((size_t)(pk0 >> 16) * Tt + (pk0 & 0xffff)) * Dd);
  uint4* r1 = (uint4*)(xg + ((size_t)(pk1 >> 16) * Tt + (pk1 & 0xffff)) * Dd);
  const float4* x4 = reinterpret_cast<const float4*>(x + (size_t)t * Dd);
#pragma unroll
  for (int it = 0; it < 2; ++it) {
    int c = lane + it * 64;          // 8-elem chunk, 0..127
    float4 a = x4[2 * c], b = x4[2 * c + 1];
    uint4 o;
    o.x = pack2bf(a.x, a.y);
    o.y = pack2bf(a.z, a.w);
    o.z = pack2bf(b.x, b.y);
    o.w = pack2bf(b.z, b.w);
    r0[c] = o;
    r1[c] = o;
  }
}

// ================== 128x128 tile, BK=32, 4 waves (2x2) — r12/r14/r18-proven ==============
#define STAGE(so_, k0)                                 \
  do {                                                 \
    glds16(aS0 + (k0), AsW + (so_) * 4096);            \
    glds16(aS1 + (k0), AsW + (so_) * 4096 + 2048);     \
    glds16(bS0 + (k0), BsW + (so_) * 4096);            \
    glds16(bS1 + (k0), BsW + (so_) * 4096 + 2048);     \
  } while (0)

#define COMPUTE(so_)                                                            \
  do {                                                                          \
    short8 af[4], bv[4];                                                        \
    _Pragma("unroll") for (int i = 0; i < 4; i++)                               \
        af[i] = *reinterpret_cast<const short8*>(                               \
            &As[(so_) * 4096 + (wm * 64 + i * 16 + fr) * 32 + gph]);            \
    _Pragma("unroll") for (int j = 0; j < 4; j++)                               \
        bv[j] = *reinterpret_cast<const short8*>(                               \
            &Bs[(so_) * 4096 + (wn * 64 + j * 16 + fr) * 32 + gph]);            \
    _Pragma("unroll") for (int i = 0; i < 4; i++)                               \
      _Pragma("unroll") for (int j = 0; j < 4; j++)                             \
          acc[i][j] = __builtin_amdgcn_mfma_f32_16x16x32_bf16(af[i], bv[j],     \
                                                              acc[i][j], 0, 0, 0); \
  } while (0)

#define PIPELINE(NKT)                                              \
  do {                                                             \
    STAGE(0, 0);                                                   \
    STAGE(1, 32);                                                  \
    for (int kt = 0; kt <= (NKT)-3; ++kt) {                        \
      int so = kt & 1;                                             \
      asm volatile("s_waitcnt vmcnt(4)" ::: "memory");             \
      __builtin_amdgcn_s_barrier();                                \
      COMPUTE(so);                                                 \
      __builtin_amdgcn_s_barrier();                                \
      STAGE(so, (kt + 2) * 32);                                    \
    }                                                              \
    asm volatile("s_waitcnt vmcnt(4)" ::: "memory");               \
    __builtin_amdgcn_s_barrier();                                  \
    COMPUTE(((NKT)-2) & 1);                                        \
    asm volatile("s_waitcnt vmcnt(0)" ::: "memory");               \
    __builtin_amdgcn_s_barrier();                                  \
    COMPUTE(((NKT)-1) & 1);                                        \
  } while (0)

// Inline per-block meta from cnt: off_e = prefix sum, m_e = ceil(ce/128)
#define EXPERT_META                                    \
  int ce = cnt[e];                                     \
  int off_e = 0;                                       \
  _Pragma("unroll") for (int i_ = 0; i_ < Ee; i_++)    \
      off_e += (i_ < e) ? cnt[i_] : 0;                 \
  int m_e = (ce + 127) >> 7;

// ---------------- GEMM1 (r18): h = gelu(xg @ W1[e]^T + b1[e]) -> bf16 ------------------
__global__ __launch_bounds__(256) void gemm1_kernel(
    const unsigned short* __restrict__ xg, const unsigned short* __restrict__ w1b,
    const float* __restrict__ b1,
    const int* __restrict__ cnt,
    unsigned short* __restrict__ hb) {
  int e = blockIdx.x & 7;
  int G = gridDim.x >> 3;
  EXPERT_META
  int span = m_e * (Hh / 128);

  __shared__ short As[2 * 4096];
  __shared__ short Bs[2 * 4096];

  int tid = threadIdx.x;
  int lane = tid & 63;
  int w = tid >> 6;
  int wm = w >> 1, wn = w & 1;
  int fr = lane & 15, kq = lane >> 4;

  int r0 = tid >> 2;
  int swz = ((tid & 3) ^ ((r0 >> 1) & 3)) << 3;
  short* AsW = &As[w * 512];
  short* BsW = &Bs[w * 512];
  int gph = (kq ^ ((fr >> 1) & 3)) << 3;
  const float* b1e = b1 + (size_t)e * Hh;

  for (int local = blockIdx.x >> 3; local < span; local += G) {
    int nt = local / m_e, mt = local % m_e;
    __syncthreads();

    const unsigned short* aS0 = xg + (size_t)e * Tt * Dd + (size_t)(mt * 128 + r0) * Dd + swz;
    const unsigned short* aS1 = aS0 + (size_t)64 * Dd;
    const unsigned short* bS0 = w1b + (size_t)e * Hh * Dd + (size_t)(nt * 128 + r0) * Dd + swz;
    const unsigned short* bS1 = bS0 + (size_t)64 * Dd;

    float biasj[4];
#pragma unroll
    for (int j = 0; j < 4; j++) biasj[j] = b1e[nt * 128 + wn * 64 + j * 16 + fr];
    asm volatile("s_waitcnt vmcnt(0)" ::: "memory");

    f32x4 acc[4][4] = {};
    PIPELINE(Dd / 32);

#pragma unroll
    for (int i = 0; i < 4; i++) {
      int rb = wm * 64 + i * 16 + kq * 4;
#pragma unroll
      for (int j = 0; j < 4; j++) {
        int col = nt * 128 + wn * 64 + j * 16 + fr;
#pragma unroll
        for (int rr = 0; rr < 4; rr++) {
          int grow = mt * 128 + rb + rr;
          if (grow < ce) {
            float v = acc[i][j][rr] + biasj[j];
            v = 0.5f * v * (1.0f + erff(v * 0.70710678118654752f));
            hb[(size_t)(off_e + grow) * Hh + col] = f2bf_bits(v);
          }
        }
      }
    }
  }
}

// ---------------- GEMM2 (r18): y[en] = h @ W2[e]^T + b2[e], plain stores ---------------
__global__ __launch_bounds__(256) void gemm2_kernel(
    const unsigned short* __restrict__ hb, const unsigned short* __restrict__ w2b,
    const float* __restrict__ b2,
    const int* __restrict__ cnt, const int* __restrict__ list,
    float* __restrict__ y) {
  int e = blockIdx.x & 7;
  int G = gridDim.x >> 3;
  EXPERT_META
  int span = m_e * (Dd / 128);

  __shared__ short As[2 * 4096];
  __shared__ short Bs[2 * 4096];

  int tid = threadIdx.x;
  int lane = tid & 63;
  int w = tid >> 6;
  int wm = w >> 1, wn = w & 1;
  int fr = lane & 15, kq = lane >> 4;

  int r0 = tid >> 2;
  int swz = ((tid & 3) ^ ((r0 >> 1) & 3)) << 3;
  short* AsW = &As[w * 512];
  short* BsW = &Bs[w * 512];
  int gph = (kq ^ ((fr >> 1) & 3)) << 3;
  const int* le = list + e * Tt;
  const float* b2e = b2 + (size_t)e * Dd;

  for (int local = blockIdx.x >> 3; local < span; local += G) {
    int nt = local / m_e, mt = local % m_e;
    __syncthreads();

    int ra0 = mt * 128 + r0;      if (ra0 >= ce) ra0 = ce - 1;
    int ra1 = mt * 128 + r0 + 64; if (ra1 >= ce) ra1 = ce - 1;
    const unsigned short* aS0 = hb + (size_t)(off_e + ra0) * Hh + swz;
    const unsigned short* aS1 = hb + (size_t)(off_e + ra1) * Hh + swz;
    const unsigned short* bS0 = w2b + (size_t)e * Dd * Hh + (size_t)(nt * 128 + r0) * Hh + swz;
    const unsigned short* bS1 = bS0 + (size_t)64 * Hh;

    float biasj[4];
#pragma unroll
    for (int j = 0; j < 4; j++) biasj[j] = b2e[nt * 128 + wn * 64 + j * 16 + fr];
    asm volatile("s_waitcnt vmcnt(0)" ::: "memory");

    f32x4 acc[4][4] = {};
    PIPELINE(Hh / 32);   // full K = 4096, 128 steps

#pragma unroll
    for (int i = 0; i < 4; i++) {
      int rb = wm * 64 + i * 16 + kq * 4;
#pragma unroll
      for (int j = 0; j < 4; j++) {
        int col = nt * 128 + wn * 64 + j * 16 + fr;
#pragma unroll
        for (int rr = 0; rr < 4; rr++) {
          int grow = mt * 128 + rb + rr;
          if (grow < ce) {
            int en = le[grow];
            y[(size_t)en * Dd + col] = acc[i][j][rr] + biasj[j];
          }
        }
      }
    }
  }
}

// ---------------- combine: out[t] = g0*y[2t] + g1*y[2t+1] ----------------
__global__ __launch_bounds__(256) void combine_kernel(
    const float* __restrict__ y, const float* __restrict__ g2, float* __restrict__ out) {
  const int C4 = Dd / 4;
  int i = blockIdx.x * blockDim.x + threadIdx.x;
  int t = i / C4;
  int c = i % C4;
  float g0 = g2[t * 2 + 0];
  float g1 = g2[t * 2 + 1];
  float4 y0 = reinterpret_cast<const float4*>(y)[(size_t)(t * 2 + 0) * C4 + c];
  float4 y1 = reinterpret_cast<const float4*>(y)[(size_t)(t * 2 + 1) * C4 + c];
  float4 o;
  o.x = g0 * y0.x + g1 * y1.x;
  o.y = g0 * y0.y + g1 * y1.y;
  o.z = g0 * y0.z + g1 * y1.z;
  o.w = g0 * y0.w + g1 * y1.w;
  reinterpret_cast<float4*>(out)[i] = o;
}

extern "C" void kernel_launch(void* const* d_in, const int* in_sizes, int n_in,
                              void* d_out, int out_size, void* d_ws, size_t ws_size,
                              hipStream_t stream) {
  const float* x  = (const float*)d_in[0];
  const float* Wr = (const float*)d_in[1];
  const float* br = (const float*)d_in[2];
  const float* W1 = (const float*)d_in[3];
  const float* b1 = (const float*)d_in[4];
  const float* W2 = (const float*)d_in[5];
  const float* b2 = (const float*)d_in[6];
  float* out = (float*)d_out;

  char* base = (char*)d_ws;
  size_t o = 0;
  auto alloc = [&](size_t n) { char* r = base + o; o += (n + 255) & ~(size_t)255; return r; };
  unsigned short* w1b = (unsigned short*)alloc((size_t)Ee * Hh * Dd * 2);
  unsigned short* w2b = (unsigned short*)alloc((size_t)Ee * Dd * Hh * 2);
  unsigned short* xg  = (unsigned short*)alloc((size_t)Ee * Tt * Dd * 2);
  unsigned short* hb  = (unsigned short*)alloc((size_t)(Tt * Kk + 256) * Hh * 2);
  int* list  = (int*)alloc((size_t)Ee * Tt * 4);
  float* g2  = (float*)alloc((size_t)Tt * Kk * 4);
  int* tokinfo = (int*)alloc(Tt * 4);
  int* pos   = (int*)alloc((size_t)Tt * Kk * 4);
  int* cnt   = (int*)alloc(Ee * 4);
  if (o > ws_size) return;  // workspace too small: fail loudly (output stays poisoned)

  // w1b (64MB) dead after gemm1; holds y[Tt*Kk][Dd] f32 (32MB).
  float* y = (float*)w1b;

  cvt_both_kernel<<<8192, 256, 0, stream>>>(W1, w1b, W2, w2b, Ee * Hh * Dd / 8);
  router_kernel<<<Tt / 4, 256, 0, stream>>>(x, Wr, br, tokinfo, g2);
  assign_kernel<<<1, 256, 0, stream>>>(tokinfo, pos, list, cnt);
  gather_kernel<<<Tt / 4, 256, 0, stream>>>(x, pos, xg);

  gemm1_kernel<<<2048, 256, 0, stream>>>(xg, w1b, b1, cnt, hb);
  gemm2_kernel<<<1024, 256, 0, stream>>>(hb, w2b, b2, cnt, list, y);
  combine_kernel<<<(Tt * Dd / 4) / 256, 256, 0, stream>>>(y, g2, out);
}

// Round 22
// 399.596 us; speedup vs baseline: 1.3497x; 1.0144x over previous
//
#include <hip/hip_runtime.h>
#include <hip/hip_bf16.h>

#define Dd 1024
#define Hh 4096
#define Ee 8
#define Tt 4096   // tokens = 2*2048
#define Kk 2

typedef __attribute__((ext_vector_type(8))) short short8;
typedef __attribute__((ext_vector_type(4))) float f32x4;

__device__ __forceinline__ unsigned short f2bf_bits(float f) {
  unsigned u = __builtin_bit_cast(unsigned, f);
  u += 0x7FFFu + ((u >> 16) & 1u);   // RNE (finite values)
  return (unsigned short)(u >> 16);
}

__device__ __forceinline__ unsigned pack2bf(float lo, float hi) {
  return (unsigned)f2bf_bits(lo) | ((unsigned)f2bf_bits(hi) << 16);
}

// Exact-erf GELU via Abramowitz-Stegun 7.1.26 (max |err(erf)| = 1.5e-7, branch-free).
// gelu(v) = 0.5 v (1 + erf(v/sqrt2)); approx error in output <= |v|*7.5e-8 << bf16 ulp.
__device__ __forceinline__ float fast_gelu(float v) {
  float z = v * 0.70710678118654752f;
  float az = fabsf(z);
  float t = __frcp_rn(1.0f + 0.3275911f * az);
  float poly = t * (0.254829592f + t * (-0.284496736f + t * (1.421413741f +
               t * (-1.453152027f + t * 1.061405429f))));
  float e = __expf(-az * az);
  float erf_az = 1.0f - poly * e;
  float erf_z = copysignf(erf_az, z);
  return 0.5f * v * (1.0f + erf_z);
}

__device__ __forceinline__ void glds16(const void* g, void* l) {
  __builtin_amdgcn_global_load_lds(
      (const __attribute__((address_space(1))) unsigned int*)g,
      (__attribute__((address_space(3))) unsigned int*)l, 16, 0, 0);
}

// ---------------- W1/W2 fp32 -> bf16 (16B stores) ----------------
__global__ __launch_bounds__(256) void cvt_both_kernel(
    const float* __restrict__ w1, unsigned short* __restrict__ w1b,
    const float* __restrict__ w2, unsigned short* __restrict__ w2b, int n8each) {
  int i = blockIdx.x * blockDim.x + threadIdx.x;
  int stride = gridDim.x * blockDim.x;
  for (; i < 2 * n8each; i += stride) {
    const float4* src = (i < n8each) ? reinterpret_cast<const float4*>(w1)
                                     : reinterpret_cast<const float4*>(w2);
    uint4* dst = (i < n8each) ? reinterpret_cast<uint4*>(w1b)
                              : reinterpret_cast<uint4*>(w2b);
    int k = (i < n8each) ? i : i - n8each;
    float4 a = src[2 * k], b = src[2 * k + 1];
    uint4 o;
    o.x = pack2bf(a.x, a.y);
    o.y = pack2bf(a.z, a.w);
    o.z = pack2bf(b.x, b.y);
    o.w = pack2bf(b.z, b.w);
    dst[k] = o;
  }
}

// ---------------- router compute: top-2 experts + gates, NO atomics ----------------
__global__ __launch_bounds__(256) void router_kernel(
    const float* __restrict__ x, const float* __restrict__ Wr, const float* __restrict__ br,
    int* __restrict__ tokinfo, float* __restrict__ g2) {
  int t = blockIdx.x * 4 + (threadIdx.x >> 6);
  int lane = threadIdx.x & 63;
  const float4* x4 = reinterpret_cast<const float4*>(x + (size_t)t * Dd);
  const float4* Wr4 = reinterpret_cast<const float4*>(Wr);
  float pe[Ee];
#pragma unroll
  for (int e = 0; e < Ee; e++) pe[e] = 0.f;
  for (int c = lane; c < Dd / 4; c += 64) {
    float4 xv = x4[c];
#pragma unroll
    for (int e = 0; e < Ee; e++) {
      float4 wv = Wr4[e * (Dd / 4) + c];
      pe[e] += xv.x * wv.x + xv.y * wv.y + xv.z * wv.z + xv.w * wv.w;
    }
  }
#pragma unroll
  for (int e = 0; e < Ee; e++) {
    float v = pe[e];
#pragma unroll
    for (int s = 32; s > 0; s >>= 1) v += __shfl_xor(v, s);
    pe[e] = v + br[e];
  }
  if (lane == 0) {
    float mx = pe[0];
#pragma unroll
    for (int e = 1; e < Ee; e++) mx = fmaxf(mx, pe[e]);
    float g[Ee];
    float sum = 0.f;
#pragma unroll
    for (int e = 0; e < Ee; e++) { g[e] = expf(pe[e] - mx); sum += g[e]; }
    float inv = 1.0f / sum;
    int e0 = 0; float g0v = g[0];
#pragma unroll
    for (int e = 1; e < Ee; e++) if (g[e] > g0v) { g0v = g[e]; e0 = e; }
    int e1 = -1; float g1v = -1.f;
#pragma unroll
    for (int e = 0; e < Ee; e++) if (e != e0 && g[e] > g1v) { g1v = g[e]; e1 = e; }
    g2[t * 2 + 0] = g0v * inv;
    g2[t * 2 + 1] = g1v * inv;
    tokinfo[t] = e0 | (e1 << 8);
  }
}

// ---------------- assign: LDS counters -> list, pos, cnt (1 block) ----------------
__global__ void assign_kernel(const int* __restrict__ tokinfo, int* __restrict__ pos,
                              int* __restrict__ list, int* __restrict__ cnt) {
  __shared__ int lc[Ee];
  int tid = threadIdx.x;
  if (tid < Ee) lc[tid] = 0;
  __syncthreads();
  for (int t = tid; t < Tt; t += 256) {
    int info = tokinfo[t];
    int e0 = info & 255, e1 = info >> 8;
    int p0 = atomicAdd(&lc[e0], 1);
    list[e0 * Tt + p0] = t * 2;
    pos[t * 2] = (e0 << 16) | p0;
    int p1 = atomicAdd(&lc[e1], 1);
    list[e1 * Tt + p1] = t * 2 + 1;
    pos[t * 2 + 1] = (e1 << 16) | p1;
  }
  __syncthreads();
  if (tid < Ee) cnt[tid] = lc[tid];
}

// ---------------- gather: x rows -> xg (bf16, contiguous per expert; 16B stores) -------
__global__ __launch_bounds__(256) void gather_kernel(
    const float* __restrict__ x, const int* __restrict__ pos,
    unsigned short* __restrict__ xg) {
  int t = blockIdx.x * 4 + (threadIdx.x >> 6);
  int lane = threadIdx.x & 63;
  int pk0 = pos[t * 2], pk1 = pos[t * 2 + 1];
  uint4* r0 = (uint4*)(xg + ((size_t)(pk0 >> 16) * Tt + (pk0 & 0xffff)) * Dd);
  uint4* r1 = (uint4*)(xg + ((size_t)(pk1 >> 16) * Tt + (pk1 & 0xffff)) * Dd);
  const float4* x4 = reinterpret_cast<const float4*>(x + (size_t)t * Dd);
#pragma unroll
  for (int it = 0; it < 2; ++it) {
    int c = lane + it * 64;          // 8-elem chunk, 0..127
    float4 a = x4[2 * c], b = x4[2 * c + 1];
    uint4 o;
    o.x = pack2bf(a.x, a.y);
    o.y = pack2bf(a.z, a.w);
    o.z = pack2bf(b.x, b.y);
    o.w = pack2bf(b.z, b.w);
    r0[c] = o;
    r1[c] = o;
  }
}

// ================== 128x128 tile, BK=32, 4 waves (2x2) — r12/r14/r18-proven ==============
#define STAGE(so_, k0)                                 \
  do {                                                 \
    glds16(aS0 + (k0), AsW + (so_) * 4096);            \
    glds16(aS1 + (k0), AsW + (so_) * 4096 + 2048);     \
    glds16(bS0 + (k0), BsW + (so_) * 4096);            \
    glds16(bS1 + (k0), BsW + (so_) * 4096 + 2048);     \
  } while (0)

#define COMPUTE(so_)                                                            \
  do {                                                                          \
    short8 af[4], bv[4];                                                        \
    _Pragma("unroll") for (int i = 0; i < 4; i++)                               \
        af[i] = *reinterpret_cast<const short8*>(                               \
            &As[(so_) * 4096 + (wm * 64 + i * 16 + fr) * 32 + gph]);            \
    _Pragma("unroll") for (int j = 0; j < 4; j++)                               \
        bv[j] = *reinterpret_cast<const short8*>(                               \
            &Bs[(so_) * 4096 + (wn * 64 + j * 16 + fr) * 32 + gph]);            \
    _Pragma("unroll") for (int i = 0; i < 4; i++)                               \
      _Pragma("unroll") for (int j = 0; j < 4; j++)                             \
          acc[i][j] = __builtin_amdgcn_mfma_f32_16x16x32_bf16(af[i], bv[j],     \
                                                              acc[i][j], 0, 0, 0); \
  } while (0)

#define PIPELINE(NKT)                                              \
  do {                                                             \
    STAGE(0, 0);                                                   \
    STAGE(1, 32);                                                  \
    for (int kt = 0; kt <= (NKT)-3; ++kt) {                        \
      int so = kt & 1;                                             \
      asm volatile("s_waitcnt vmcnt(4)" ::: "memory");             \
      __builtin_amdgcn_s_barrier();                                \
      COMPUTE(so);                                                 \
      __builtin_amdgcn_s_barrier();                                \
      STAGE(so, (kt + 2) * 32);                                    \
    }                                                              \
    asm volatile("s_waitcnt vmcnt(4)" ::: "memory");               \
    __builtin_amdgcn_s_barrier();                                  \
    COMPUTE(((NKT)-2) & 1);                                        \
    asm volatile("s_waitcnt vmcnt(0)" ::: "memory");               \
    __builtin_amdgcn_s_barrier();                                  \
    COMPUTE(((NKT)-1) & 1);                                        \
  } while (0)

// Inline per-block meta from cnt: off_e = prefix sum, m_e = ceil(ce/128)
#define EXPERT_META                                    \
  int ce = cnt[e];                                     \
  int off_e = 0;                                       \
  _Pragma("unroll") for (int i_ = 0; i_ < Ee; i_++)    \
      off_e += (i_ < e) ? cnt[i_] : 0;                 \
  int m_e = (ce + 127) >> 7;

// ---------------- GEMM1: h = gelu(xg @ W1[e]^T + b1[e]) -> bf16 (fast-gelu epilogue) ---
__global__ __launch_bounds__(256) void gemm1_kernel(
    const unsigned short* __restrict__ xg, const unsigned short* __restrict__ w1b,
    const float* __restrict__ b1,
    const int* __restrict__ cnt,
    unsigned short* __restrict__ hb) {
  int e = blockIdx.x & 7;
  int G = gridDim.x >> 3;
  EXPERT_META
  int span = m_e * (Hh / 128);

  __shared__ short As[2 * 4096];
  __shared__ short Bs[2 * 4096];

  int tid = threadIdx.x;
  int lane = tid & 63;
  int w = tid >> 6;
  int wm = w >> 1, wn = w & 1;
  int fr = lane & 15, kq = lane >> 4;

  int r0 = tid >> 2;
  int swz = ((tid & 3) ^ ((r0 >> 1) & 3)) << 3;
  short* AsW = &As[w * 512];
  short* BsW = &Bs[w * 512];
  int gph = (kq ^ ((fr >> 1) & 3)) << 3;
  const float* b1e = b1 + (size_t)e * Hh;

  for (int local = blockIdx.x >> 3; local < span; local += G) {
    int nt = local / m_e, mt = local % m_e;
    __syncthreads();

    const unsigned short* aS0 = xg + (size_t)e * Tt * Dd + (size_t)(mt * 128 + r0) * Dd + swz;
    const unsigned short* aS1 = aS0 + (size_t)64 * Dd;
    const unsigned short* bS0 = w1b + (size_t)e * Hh * Dd + (size_t)(nt * 128 + r0) * Dd + swz;
    const unsigned short* bS1 = bS0 + (size_t)64 * Dd;

    float biasj[4];
#pragma unroll
    for (int j = 0; j < 4; j++) biasj[j] = b1e[nt * 128 + wn * 64 + j * 16 + fr];
    asm volatile("s_waitcnt vmcnt(0)" ::: "memory");

    f32x4 acc[4][4] = {};
    PIPELINE(Dd / 32);

#pragma unroll
    for (int i = 0; i < 4; i++) {
      int rb = wm * 64 + i * 16 + kq * 4;
#pragma unroll
      for (int j = 0; j < 4; j++) {
        int col = nt * 128 + wn * 64 + j * 16 + fr;
#pragma unroll
        for (int rr = 0; rr < 4; rr++) {
          int grow = mt * 128 + rb + rr;
          if (grow < ce) {
            float v = fast_gelu(acc[i][j][rr] + biasj[j]);
            hb[(size_t)(off_e + grow) * Hh + col] = f2bf_bits(v);
          }
        }
      }
    }
  }
}

// ---------------- GEMM2 (r18): y[en] = h @ W2[e]^T + b2[e], plain stores ---------------
__global__ __launch_bounds__(256) void gemm2_kernel(
    const unsigned short* __restrict__ hb, const unsigned short* __restrict__ w2b,
    const float* __restrict__ b2,
    const int* __restrict__ cnt, const int* __restrict__ list,
    float* __restrict__ y) {
  int e = blockIdx.x & 7;
  int G = gridDim.x >> 3;
  EXPERT_META
  int span = m_e * (Dd / 128);

  __shared__ short As[2 * 4096];
  __shared__ short Bs[2 * 4096];

  int tid = threadIdx.x;
  int lane = tid & 63;
  int w = tid >> 6;
  int wm = w >> 1, wn = w & 1;
  int fr = lane & 15, kq = lane >> 4;

  int r0 = tid >> 2;
  int swz = ((tid & 3) ^ ((r0 >> 1) & 3)) << 3;
  short* AsW = &As[w * 512];
  short* BsW = &Bs[w * 512];
  int gph = (kq ^ ((fr >> 1) & 3)) << 3;
  const int* le = list + e * Tt;
  const float* b2e = b2 + (size_t)e * Dd;

  for (int local = blockIdx.x >> 3; local < span; local += G) {
    int nt = local / m_e, mt = local % m_e;
    __syncthreads();

    int ra0 = mt * 128 + r0;      if (ra0 >= ce) ra0 = ce - 1;
    int ra1 = mt * 128 + r0 + 64; if (ra1 >= ce) ra1 = ce - 1;
    const unsigned short* aS0 = hb + (size_t)(off_e + ra0) * Hh + swz;
    const unsigned short* aS1 = hb + (size_t)(off_e + ra1) * Hh + swz;
    const unsigned short* bS0 = w2b + (size_t)e * Dd * Hh + (size_t)(nt * 128 + r0) * Hh + swz;
    const unsigned short* bS1 = bS0 + (size_t)64 * Hh;

    float biasj[4];
#pragma unroll
    for (int j = 0; j < 4; j++) biasj[j] = b2e[nt * 128 + wn * 64 + j * 16 + fr];
    asm volatile("s_waitcnt vmcnt(0)" ::: "memory");

    f32x4 acc[4][4] = {};
    PIPELINE(Hh / 32);   // full K = 4096, 128 steps

#pragma unroll
    for (int i = 0; i < 4; i++) {
      int rb = wm * 64 + i * 16 + kq * 4;
#pragma unroll
      for (int j = 0; j < 4; j++) {
        int col = nt * 128 + wn * 64 + j * 16 + fr;
#pragma unroll
        for (int rr = 0; rr < 4; rr++) {
          int grow = mt * 128 + rb + rr;
          if (grow < ce) {
            int en = le[grow];
            y[(size_t)en * Dd + col] = acc[i][j][rr] + biasj[j];
          }
        }
      }
    }
  }
}

// ---------------- combine: out[t] = g0*y[2t] + g1*y[2t+1] ----------------
__global__ __launch_bounds__(256) void combine_kernel(
    const float* __restrict__ y, const float* __restrict__ g2, float* __restrict__ out) {
  const int C4 = Dd / 4;
  int i = blockIdx.x * blockDim.x + threadIdx.x;
  int t = i / C4;
  int c = i % C4;
  float g0 = g2[t * 2 + 0];
  float g1 = g2[t * 2 + 1];
  float4 y0 = reinterpret_cast<const float4*>(y)[(size_t)(t * 2 + 0) * C4 + c];
  float4 y1 = reinterpret_cast<const float4*>(y)[(size_t)(t * 2 + 1) * C4 + c];
  float4 o;
  o.x = g0 * y0.x + g1 * y1.x;
  o.y = g0 * y0.y + g1 * y1.y;
  o.z = g0 * y0.z + g1 * y1.z;
  o.w = g0 * y0.w + g1 * y1.w;
  reinterpret_cast<float4*>(out)[i] = o;
}

extern "C" void kernel_launch(void* const* d_in, const int* in_sizes, int n_in,
                              void* d_out, int out_size, void* d_ws, size_t ws_size,
                              hipStream_t stream) {
  const float* x  = (const float*)d_in[0];
  const float* Wr = (const float*)d_in[1];
  const float* br = (const float*)d_in[2];
  const float* W1 = (const float*)d_in[3];
  const float* b1 = (const float*)d_in[4];
  const float* W2 = (const float*)d_in[5];
  const float* b2 = (const float*)d_in[6];
  float* out = (float*)d_out;

  char* base = (char*)d_ws;
  size_t o = 0;
  auto alloc = [&](size_t n) { char* r = base + o; o += (n + 255) & ~(size_t)255; return r; };
  unsigned short* w1b = (unsigned short*)alloc((size_t)Ee * Hh * Dd * 2);
  unsigned short* w2b = (unsigned short*)alloc((size_t)Ee * Dd * Hh * 2);
  unsigned short* xg  = (unsigned short*)alloc((size_t)Ee * Tt * Dd * 2);
  unsigned short* hb  = (unsigned short*)alloc((size_t)(Tt * Kk + 256) * Hh * 2);
  int* list  = (int*)alloc((size_t)Ee * Tt * 4);
  float* g2  = (float*)alloc((size_t)Tt * Kk * 4);
  int* tokinfo = (int*)alloc(Tt * 4);
  int* pos   = (int*)alloc((size_t)Tt * Kk * 4);
  int* cnt   = (int*)alloc(Ee * 4);
  if (o > ws_size) return;  // workspace too small: fail loudly (output stays poisoned)

  // w1b (64MB) dead after gemm1; holds y[Tt*Kk][Dd] f32 (32MB).
  float* y = (float*)w1b;

  cvt_both_kernel<<<8192, 256, 0, stream>>>(W1, w1b, W2, w2b, Ee * Hh * Dd / 8);
  router_kernel<<<Tt / 4, 256, 0, stream>>>(x, Wr, br, tokinfo, g2);
  assign_kernel<<<1, 256, 0, stream>>>(tokinfo, pos, list, cnt);
  gather_kernel<<<Tt / 4, 256, 0, stream>>>(x, pos, xg);

  gemm1_kernel<<<2048, 256, 0, stream>>>(xg, w1b, b1, cnt, hb);
  gemm2_kernel<<<1024, 256, 0, stream>>>(hb, w2b, b2, cnt, list, y);
  combine_kernel<<<(Tt * Dd / 4) / 256, 256, 0, stream>>>(y, g2, out);
}

// Round 23
// 397.849 us; speedup vs baseline: 1.3557x; 1.0044x over previous
//
#include <hip/hip_runtime.h>
#include <hip/hip_bf16.h>

#define Dd 1024
#define Hh 4096
#define Ee 8
#define Tt 4096   // tokens = 2*2048
#define Kk 2

typedef __attribute__((ext_vector_type(8))) short short8;
typedef __attribute__((ext_vector_type(4))) float f32x4;

__device__ __forceinline__ unsigned short f2bf_bits(float f) {
  unsigned u = __builtin_bit_cast(unsigned, f);
  u += 0x7FFFu + ((u >> 16) & 1u);   // RNE (finite values)
  return (unsigned short)(u >> 16);
}

__device__ __forceinline__ unsigned pack2bf(float lo, float hi) {
  return (unsigned)f2bf_bits(lo) | ((unsigned)f2bf_bits(hi) << 16);
}

// Exact-erf GELU via Abramowitz-Stegun 7.1.26 (max |err(erf)| = 1.5e-7, branch-free).
__device__ __forceinline__ float fast_gelu(float v) {
  float z = v * 0.70710678118654752f;
  float az = fabsf(z);
  float t = __frcp_rn(1.0f + 0.3275911f * az);
  float poly = t * (0.254829592f + t * (-0.284496736f + t * (1.421413741f +
               t * (-1.453152027f + t * 1.061405429f))));
  float e = __expf(-az * az);
  float erf_az = 1.0f - poly * e;
  float erf_z = copysignf(erf_az, z);
  return 0.5f * v * (1.0f + erf_z);
}

__device__ __forceinline__ void glds16(const void* g, void* l) {
  __builtin_amdgcn_global_load_lds(
      (const __attribute__((address_space(1))) unsigned int*)g,
      (__attribute__((address_space(3))) unsigned int*)l, 16, 0, 0);
}

// ======= fused: router (blocks 0..1023, atomic-free) + W1/W2 cvt (rest) =======
// r20's fusion failed because the OLD router serialized on 8192 global atomics;
// r21's router is atomic-free, so the router now hides inside cvt's BW-bound window.
__global__ __launch_bounds__(256) void cvt_router_kernel(
    const float* __restrict__ x, const float* __restrict__ Wr, const float* __restrict__ br,
    const float* __restrict__ w1, unsigned short* __restrict__ w1b,
    const float* __restrict__ w2, unsigned short* __restrict__ w2b,
    int* __restrict__ tokinfo, float* __restrict__ g2) {
  const int RB = Tt / 4;   // 1024 router blocks
  if (blockIdx.x < RB) {
    int t = blockIdx.x * 4 + (threadIdx.x >> 6);
    int lane = threadIdx.x & 63;
    const float4* x4 = reinterpret_cast<const float4*>(x + (size_t)t * Dd);
    const float4* Wr4 = reinterpret_cast<const float4*>(Wr);
    float pe[Ee];
#pragma unroll
    for (int e = 0; e < Ee; e++) pe[e] = 0.f;
    for (int c = lane; c < Dd / 4; c += 64) {
      float4 xv = x4[c];
#pragma unroll
      for (int e = 0; e < Ee; e++) {
        float4 wv = Wr4[e * (Dd / 4) + c];
        pe[e] += xv.x * wv.x + xv.y * wv.y + xv.z * wv.z + xv.w * wv.w;
      }
    }
#pragma unroll
    for (int e = 0; e < Ee; e++) {
      float v = pe[e];
#pragma unroll
      for (int s = 32; s > 0; s >>= 1) v += __shfl_xor(v, s);
      pe[e] = v + br[e];
    }
    if (lane == 0) {
      float mx = pe[0];
#pragma unroll
      for (int e = 1; e < Ee; e++) mx = fmaxf(mx, pe[e]);
      float g[Ee];
      float sum = 0.f;
#pragma unroll
      for (int e = 0; e < Ee; e++) { g[e] = expf(pe[e] - mx); sum += g[e]; }
      float inv = 1.0f / sum;
      int e0 = 0; float g0v = g[0];
#pragma unroll
      for (int e = 1; e < Ee; e++) if (g[e] > g0v) { g0v = g[e]; e0 = e; }
      int e1 = -1; float g1v = -1.f;
#pragma unroll
      for (int e = 0; e < Ee; e++) if (e != e0 && g[e] > g1v) { g1v = g[e]; e1 = e; }
      g2[t * 2 + 0] = g0v * inv;
      g2[t * 2 + 1] = g1v * inv;
      tokinfo[t] = e0 | (e1 << 8);
    }
  } else {
    const int n8each = Ee * Hh * Dd / 8;
    int i = (blockIdx.x - RB) * 256 + threadIdx.x;
    int stride = (gridDim.x - RB) * 256;
    for (; i < 2 * n8each; i += stride) {
      const float4* src = (i < n8each) ? reinterpret_cast<const float4*>(w1)
                                       : reinterpret_cast<const float4*>(w2);
      uint4* dst = (i < n8each) ? reinterpret_cast<uint4*>(w1b)
                                : reinterpret_cast<uint4*>(w2b);
      int k = (i < n8each) ? i : i - n8each;
      float4 a = src[2 * k], b = src[2 * k + 1];
      uint4 o;
      o.x = pack2bf(a.x, a.y);
      o.y = pack2bf(a.z, a.w);
      o.z = pack2bf(b.x, b.y);
      o.w = pack2bf(b.z, b.w);
      dst[k] = o;
    }
  }
}

// ---------------- assign: LDS counters -> list, pos, cnt (1 block) ----------------
__global__ void assign_kernel(const int* __restrict__ tokinfo, int* __restrict__ pos,
                              int* __restrict__ list, int* __restrict__ cnt) {
  __shared__ int lc[Ee];
  int tid = threadIdx.x;
  if (tid < Ee) lc[tid] = 0;
  __syncthreads();
  for (int t = tid; t < Tt; t += 256) {
    int info = tokinfo[t];
    int e0 = info & 255, e1 = info >> 8;
    int p0 = atomicAdd(&lc[e0], 1);
    list[e0 * Tt + p0] = t * 2;
    pos[t * 2] = (e0 << 16) | p0;
    int p1 = atomicAdd(&lc[e1], 1);
    list[e1 * Tt + p1] = t * 2 + 1;
    pos[t * 2 + 1] = (e1 << 16) | p1;
  }
  __syncthreads();
  if (tid < Ee) cnt[tid] = lc[tid];
}

// ---------------- gather: x rows -> xg (bf16, contiguous per expert; 16B stores) -------
__global__ __launch_bounds__(256) void gather_kernel(
    const float* __restrict__ x, const int* __restrict__ pos,
    unsigned short* __restrict__ xg) {
  int t = blockIdx.x * 4 + (threadIdx.x >> 6);
  int lane = threadIdx.x & 63;
  int pk0 = pos[t * 2], pk1 = pos[t * 2 + 1];
  uint4* r0 = (uint4*)(xg + ((size_t)(pk0 >> 16) * Tt + (pk0 & 0xffff)) * Dd);
  uint4* r1 = (uint4*)(xg + ((size_t)(pk1 >> 16) * Tt + (pk1 & 0xffff)) * Dd);
  const float4* x4 = reinterpret_cast<const float4*>(x + (size_t)t * Dd);
#pragma unroll
  for (int it = 0; it < 2; ++it) {
    int c = lane + it * 64;          // 8-elem chunk, 0..127
    float4 a = x4[2 * c], b = x4[2 * c + 1];
    uint4 o;
    o.x = pack2bf(a.x, a.y);
    o.y = pack2bf(a.z, a.w);
    o.z = pack2bf(b.x, b.y);
    o.w = pack2bf(b.z, b.w);
    r0[c] = o;
    r1[c] = o;
  }
}

// ================== 128x128 tile, BK=32, 4 waves (2x2) — r12/r14/r18-proven ==============
#define STAGE(so_, k0)                                 \
  do {                                                 \
    glds16(aS0 + (k0), AsW + (so_) * 4096);            \
    glds16(aS1 + (k0), AsW + (so_) * 4096 + 2048);     \
    glds16(bS0 + (k0), BsW + (so_) * 4096);            \
    glds16(bS1 + (k0), BsW + (so_) * 4096 + 2048);     \
  } while (0)

#define COMPUTE(so_)                                                            \
  do {                                                                          \
    short8 af[4], bv[4];                                                        \
    _Pragma("unroll") for (int i = 0; i < 4; i++)                               \
        af[i] = *reinterpret_cast<const short8*>(                               \
            &As[(so_) * 4096 + (wm * 64 + i * 16 + fr) * 32 + gph]);            \
    _Pragma("unroll") for (int j = 0; j < 4; j++)                               \
        bv[j] = *reinterpret_cast<const short8*>(                               \
            &Bs[(so_) * 4096 + (wn * 64 + j * 16 + fr) * 32 + gph]);            \
    _Pragma("unroll") for (int i = 0; i < 4; i++)                               \
      _Pragma("unroll") for (int j = 0; j < 4; j++)                             \
          acc[i][j] = __builtin_amdgcn_mfma_f32_16x16x32_bf16(af[i], bv[j],     \
                                                              acc[i][j], 0, 0, 0); \
  } while (0)

#define PIPELINE(NKT)                                              \
  do {                                                             \
    STAGE(0, 0);                                                   \
    STAGE(1, 32);                                                  \
    for (int kt = 0; kt <= (NKT)-3; ++kt) {                        \
      int so = kt & 1;                                             \
      asm volatile("s_waitcnt vmcnt(4)" ::: "memory");             \
      __builtin_amdgcn_s_barrier();                                \
      COMPUTE(so);                                                 \
      __builtin_amdgcn_s_barrier();                                \
      STAGE(so, (kt + 2) * 32);                                    \
    }                                                              \
    asm volatile("s_waitcnt vmcnt(4)" ::: "memory");               \
    __builtin_amdgcn_s_barrier();                                  \
    COMPUTE(((NKT)-2) & 1);                                        \
    asm volatile("s_waitcnt vmcnt(0)" ::: "memory");               \
    __builtin_amdgcn_s_barrier();                                  \
    COMPUTE(((NKT)-1) & 1);                                        \
  } while (0)

// Inline per-block meta from cnt: off_e = prefix sum, m_e = ceil(ce/128)
#define EXPERT_META                                    \
  int ce = cnt[e];                                     \
  int off_e = 0;                                       \
  _Pragma("unroll") for (int i_ = 0; i_ < Ee; i_++)    \
      off_e += (i_ < e) ? cnt[i_] : 0;                 \
  int m_e = (ce + 127) >> 7;

// ---------------- GEMM1: h = gelu(xg @ W1[e]^T + b1[e]) -> bf16 (fast-gelu epilogue) ---
__global__ __launch_bounds__(256) void gemm1_kernel(
    const unsigned short* __restrict__ xg, const unsigned short* __restrict__ w1b,
    const float* __restrict__ b1,
    const int* __restrict__ cnt,
    unsigned short* __restrict__ hb) {
  int e = blockIdx.x & 7;
  int G = gridDim.x >> 3;
  EXPERT_META
  int span = m_e * (Hh / 128);

  __shared__ short As[2 * 4096];
  __shared__ short Bs[2 * 4096];

  int tid = threadIdx.x;
  int lane = tid & 63;
  int w = tid >> 6;
  int wm = w >> 1, wn = w & 1;
  int fr = lane & 15, kq = lane >> 4;

  int r0 = tid >> 2;
  int swz = ((tid & 3) ^ ((r0 >> 1) & 3)) << 3;
  short* AsW = &As[w * 512];
  short* BsW = &Bs[w * 512];
  int gph = (kq ^ ((fr >> 1) & 3)) << 3;
  const float* b1e = b1 + (size_t)e * Hh;

  for (int local = blockIdx.x >> 3; local < span; local += G) {
    int nt = local / m_e, mt = local % m_e;
    __syncthreads();

    const unsigned short* aS0 = xg + (size_t)e * Tt * Dd + (size_t)(mt * 128 + r0) * Dd + swz;
    const unsigned short* aS1 = aS0 + (size_t)64 * Dd;
    const unsigned short* bS0 = w1b + (size_t)e * Hh * Dd + (size_t)(nt * 128 + r0) * Dd + swz;
    const unsigned short* bS1 = bS0 + (size_t)64 * Dd;

    float biasj[4];
#pragma unroll
    for (int j = 0; j < 4; j++) biasj[j] = b1e[nt * 128 + wn * 64 + j * 16 + fr];
    asm volatile("s_waitcnt vmcnt(0)" ::: "memory");

    f32x4 acc[4][4] = {};
    PIPELINE(Dd / 32);

#pragma unroll
    for (int i = 0; i < 4; i++) {
      int rb = wm * 64 + i * 16 + kq * 4;
#pragma unroll
      for (int j = 0; j < 4; j++) {
        int col = nt * 128 + wn * 64 + j * 16 + fr;
#pragma unroll
        for (int rr = 0; rr < 4; rr++) {
          int grow = mt * 128 + rb + rr;
          if (grow < ce) {
            float v = fast_gelu(acc[i][j][rr] + biasj[j]);
            hb[(size_t)(off_e + grow) * Hh + col] = f2bf_bits(v);
          }
        }
      }
    }
  }
}

// ---------------- GEMM2 (r18): y[en] = h @ W2[e]^T + b2[e], plain stores ---------------
__global__ __launch_bounds__(256) void gemm2_kernel(
    const unsigned short* __restrict__ hb, const unsigned short* __restrict__ w2b,
    const float* __restrict__ b2,
    const int* __restrict__ cnt, const int* __restrict__ list,
    float* __restrict__ y) {
  int e = blockIdx.x & 7;
  int G = gridDim.x >> 3;
  EXPERT_META
  int span = m_e * (Dd / 128);

  __shared__ short As[2 * 4096];
  __shared__ short Bs[2 * 4096];

  int tid = threadIdx.x;
  int lane = tid & 63;
  int w = tid >> 6;
  int wm = w >> 1, wn = w & 1;
  int fr = lane & 15, kq = lane >> 4;

  int r0 = tid >> 2;
  int swz = ((tid & 3) ^ ((r0 >> 1) & 3)) << 3;
  short* AsW = &As[w * 512];
  short* BsW = &Bs[w * 512];
  int gph = (kq ^ ((fr >> 1) & 3)) << 3;
  const int* le = list + e * Tt;
  const float* b2e = b2 + (size_t)e * Dd;

  for (int local = blockIdx.x >> 3; local < span; local += G) {
    int nt = local / m_e, mt = local % m_e;
    __syncthreads();

    int ra0 = mt * 128 + r0;      if (ra0 >= ce) ra0 = ce - 1;
    int ra1 = mt * 128 + r0 + 64; if (ra1 >= ce) ra1 = ce - 1;
    const unsigned short* aS0 = hb + (size_t)(off_e + ra0) * Hh + swz;
    const unsigned short* aS1 = hb + (size_t)(off_e + ra1) * Hh + swz;
    const unsigned short* bS0 = w2b + (size_t)e * Dd * Hh + (size_t)(nt * 128 + r0) * Hh + swz;
    const unsigned short* bS1 = bS0 + (size_t)64 * Hh;

    float biasj[4];
#pragma unroll
    for (int j = 0; j < 4; j++) biasj[j] = b2e[nt * 128 + wn * 64 + j * 16 + fr];
    asm volatile("s_waitcnt vmcnt(0)" ::: "memory");

    f32x4 acc[4][4] = {};
    PIPELINE(Hh / 32);   // full K = 4096, 128 steps

#pragma unroll
    for (int i = 0; i < 4; i++) {
      int rb = wm * 64 + i * 16 + kq * 4;
#pragma unroll
      for (int j = 0; j < 4; j++) {
        int col = nt * 128 + wn * 64 + j * 16 + fr;
#pragma unroll
        for (int rr = 0; rr < 4; rr++) {
          int grow = mt * 128 + rb + rr;
          if (grow < ce) {
            int en = le[grow];
            y[(size_t)en * Dd + col] = acc[i][j][rr] + biasj[j];
          }
        }
      }
    }
  }
}

// ---------------- combine: out[t] = g0*y[2t] + g1*y[2t+1] ----------------
__global__ __launch_bounds__(256) void combine_kernel(
    const float* __restrict__ y, const float* __restrict__ g2, float* __restrict__ out) {
  const int C4 = Dd / 4;
  int i = blockIdx.x * blockDim.x + threadIdx.x;
  int t = i / C4;
  int c = i % C4;
  float g0 = g2[t * 2 + 0];
  float g1 = g2[t * 2 + 1];
  float4 y0 = reinterpret_cast<const float4*>(y)[(size_t)(t * 2 + 0) * C4 + c];
  float4 y1 = reinterpret_cast<const float4*>(y)[(size_t)(t * 2 + 1) * C4 + c];
  float4 o;
  o.x = g0 * y0.x + g1 * y1.x;
  o.y = g0 * y0.y + g1 * y1.y;
  o.z = g0 * y0.z + g1 * y1.z;
  o.w = g0 * y0.w + g1 * y1.w;
  reinterpret_cast<float4*>(out)[i] = o;
}

extern "C" void kernel_launch(void* const* d_in, const int* in_sizes, int n_in,
                              void* d_out, int out_size, void* d_ws, size_t ws_size,
                              hipStream_t stream) {
  const float* x  = (const float*)d_in[0];
  const float* Wr = (const float*)d_in[1];
  const float* br = (const float*)d_in[2];
  const float* W1 = (const float*)d_in[3];
  const float* b1 = (const float*)d_in[4];
  const float* W2 = (const float*)d_in[5];
  const float* b2 = (const float*)d_in[6];
  float* out = (float*)d_out;

  char* base = (char*)d_ws;
  size_t o = 0;
  auto alloc = [&](size_t n) { char* r = base + o; o += (n + 255) & ~(size_t)255; return r; };
  unsigned short* w1b = (unsigned short*)alloc((size_t)Ee * Hh * Dd * 2);
  unsigned short* w2b = (unsigned short*)alloc((size_t)Ee * Dd * Hh * 2);
  unsigned short* xg  = (unsigned short*)alloc((size_t)Ee * Tt * Dd * 2);
  unsigned short* hb  = (unsigned short*)alloc((size_t)(Tt * Kk + 256) * Hh * 2);
  int* list  = (int*)alloc((size_t)Ee * Tt * 4);
  float* g2  = (float*)alloc((size_t)Tt * Kk * 4);
  int* tokinfo = (int*)alloc(Tt * 4);
  int* pos   = (int*)alloc((size_t)Tt * Kk * 4);
  int* cnt   = (int*)alloc(Ee * 4);
  if (o > ws_size) return;  // workspace too small: fail loudly (output stays poisoned)

  // w1b (64MB) dead after gemm1; holds y[Tt*Kk][Dd] f32 (32MB).
  float* y = (float*)w1b;

  cvt_router_kernel<<<1024 + 8192, 256, 0, stream>>>(x, Wr, br, W1, w1b, W2, w2b,
                                                     tokinfo, g2);
  assign_kernel<<<1, 256, 0, stream>>>(tokinfo, pos, list, cnt);
  gather_kernel<<<Tt / 4, 256, 0, stream>>>(x, pos, xg);

  gemm1_kernel<<<2048, 256, 0, stream>>>(xg, w1b, b1, cnt, hb);
  gemm2_kernel<<<1024, 256, 0, stream>>>(hb, w2b, b2, cnt, list, y);
  combine_kernel<<<(Tt * Dd / 4) / 256, 256, 0, stream>>>(y, g2, out);
}

// Round 24
// 371.879 us; speedup vs baseline: 1.4503x; 1.0698x over previous
//
#include <hip/hip_runtime.h>
#include <hip/hip_bf16.h>

#define Dd 1024
#define Hh 4096
#define Ee 8
#define Tt 4096   // tokens = 2*2048
#define Kk 2

typedef __attribute__((ext_vector_type(8))) short short8;
typedef __attribute__((ext_vector_type(4))) float f32x4;

__device__ __forceinline__ unsigned short f2bf_bits(float f) {
  unsigned u = __builtin_bit_cast(unsigned, f);
  u += 0x7FFFu + ((u >> 16) & 1u);   // RNE (finite values)
  return (unsigned short)(u >> 16);
}

__device__ __forceinline__ unsigned pack2bf(float lo, float hi) {
  return (unsigned)f2bf_bits(lo) | ((unsigned)f2bf_bits(hi) << 16);
}

// Exact-erf GELU via Abramowitz-Stegun 7.1.26 (max |err(erf)| = 1.5e-7, branch-free).
__device__ __forceinline__ float fast_gelu(float v) {
  float z = v * 0.70710678118654752f;
  float az = fabsf(z);
  float t = __frcp_rn(1.0f + 0.3275911f * az);
  float poly = t * (0.254829592f + t * (-0.284496736f + t * (1.421413741f +
               t * (-1.453152027f + t * 1.061405429f))));
  float e = __expf(-az * az);
  float erf_az = 1.0f - poly * e;
  float erf_z = copysignf(erf_az, z);
  return 0.5f * v * (1.0f + erf_z);
}

__device__ __forceinline__ void glds16(const void* g, void* l) {
  __builtin_amdgcn_global_load_lds(
      (const __attribute__((address_space(1))) unsigned int*)g,
      (__attribute__((address_space(3))) unsigned int*)l, 16, 0, 0);
}

// ======= fused: router (blocks 0..1023, atomic-free) + W1 cvt (rest) =======
__global__ __launch_bounds__(256) void cvt_router_kernel(
    const float* __restrict__ x, const float* __restrict__ Wr, const float* __restrict__ br,
    const float* __restrict__ w1, unsigned short* __restrict__ w1b,
    int* __restrict__ tokinfo, float* __restrict__ g2) {
  const int RB = Tt / 4;   // 1024 router blocks
  if (blockIdx.x < RB) {
    int t = blockIdx.x * 4 + (threadIdx.x >> 6);
    int lane = threadIdx.x & 63;
    const float4* x4 = reinterpret_cast<const float4*>(x + (size_t)t * Dd);
    const float4* Wr4 = reinterpret_cast<const float4*>(Wr);
    float pe[Ee];
#pragma unroll
    for (int e = 0; e < Ee; e++) pe[e] = 0.f;
    for (int c = lane; c < Dd / 4; c += 64) {
      float4 xv = x4[c];
#pragma unroll
      for (int e = 0; e < Ee; e++) {
        float4 wv = Wr4[e * (Dd / 4) + c];
        pe[e] += xv.x * wv.x + xv.y * wv.y + xv.z * wv.z + xv.w * wv.w;
      }
    }
#pragma unroll
    for (int e = 0; e < Ee; e++) {
      float v = pe[e];
#pragma unroll
      for (int s = 32; s > 0; s >>= 1) v += __shfl_xor(v, s);
      pe[e] = v + br[e];
    }
    if (lane == 0) {
      float mx = pe[0];
#pragma unroll
      for (int e = 1; e < Ee; e++) mx = fmaxf(mx, pe[e]);
      float g[Ee];
      float sum = 0.f;
#pragma unroll
      for (int e = 0; e < Ee; e++) { g[e] = expf(pe[e] - mx); sum += g[e]; }
      float inv = 1.0f / sum;
      int e0 = 0; float g0v = g[0];
#pragma unroll
      for (int e = 1; e < Ee; e++) if (g[e] > g0v) { g0v = g[e]; e0 = e; }
      int e1 = -1; float g1v = -1.f;
#pragma unroll
      for (int e = 0; e < Ee; e++) if (e != e0 && g[e] > g1v) { g1v = g[e]; e1 = e; }
      g2[t * 2 + 0] = g0v * inv;
      g2[t * 2 + 1] = g1v * inv;
      tokinfo[t] = e0 | (e1 << 8);
    }
  } else {
    const int n8 = Ee * Hh * Dd / 8;
    int i = (blockIdx.x - RB) * 256 + threadIdx.x;
    int stride = (gridDim.x - RB) * 256;
    const float4* src = reinterpret_cast<const float4*>(w1);
    uint4* dst = reinterpret_cast<uint4*>(w1b);
    for (; i < n8; i += stride) {
      float4 a = src[2 * i], b = src[2 * i + 1];
      uint4 o;
      o.x = pack2bf(a.x, a.y);
      o.y = pack2bf(a.z, a.w);
      o.z = pack2bf(b.x, b.y);
      o.w = pack2bf(b.z, b.w);
      dst[i] = o;
    }
  }
}

// ---------------- assign: LDS counters -> list, pos, cnt (1 block) ----------------
__global__ void assign_kernel(const int* __restrict__ tokinfo, int* __restrict__ pos,
                              int* __restrict__ list, int* __restrict__ cnt) {
  __shared__ int lc[Ee];
  int tid = threadIdx.x;
  if (tid < Ee) lc[tid] = 0;
  __syncthreads();
  for (int t = tid; t < Tt; t += 256) {
    int info = tokinfo[t];
    int e0 = info & 255, e1 = info >> 8;
    int p0 = atomicAdd(&lc[e0], 1);
    list[e0 * Tt + p0] = t * 2;
    pos[t * 2] = (e0 << 16) | p0;
    int p1 = atomicAdd(&lc[e1], 1);
    list[e1 * Tt + p1] = t * 2 + 1;
    pos[t * 2 + 1] = (e1 << 16) | p1;
  }
  __syncthreads();
  if (tid < Ee) cnt[tid] = lc[tid];
}

// ---------------- gather: x rows -> xg (bf16, contiguous per expert; 16B stores) -------
__global__ __launch_bounds__(256) void gather_kernel(
    const float* __restrict__ x, const int* __restrict__ pos,
    unsigned short* __restrict__ xg) {
  int t = blockIdx.x * 4 + (threadIdx.x >> 6);
  int lane = threadIdx.x & 63;
  int pk0 = pos[t * 2], pk1 = pos[t * 2 + 1];
  uint4* r0 = (uint4*)(xg + ((size_t)(pk0 >> 16) * Tt + (pk0 & 0xffff)) * Dd);
  uint4* r1 = (uint4*)(xg + ((size_t)(pk1 >> 16) * Tt + (pk1 & 0xffff)) * Dd);
  const float4* x4 = reinterpret_cast<const float4*>(x + (size_t)t * Dd);
#pragma unroll
  for (int it = 0; it < 2; ++it) {
    int c = lane + it * 64;          // 8-elem chunk, 0..127
    float4 a = x4[2 * c], b = x4[2 * c + 1];
    uint4 o;
    o.x = pack2bf(a.x, a.y);
    o.y = pack2bf(a.z, a.w);
    o.z = pack2bf(b.x, b.y);
    o.w = pack2bf(b.z, b.w);
    r0[c] = o;
    r1[c] = o;
  }
}

// ================== 128x128 tile, BK=32, 4 waves (2x2) — r12/r14/r18-proven ==============
#define STAGE(so_, k0)                                 \
  do {                                                 \
    glds16(aS0 + (k0), AsW + (so_) * 4096);            \
    glds16(aS1 + (k0), AsW + (so_) * 4096 + 2048);     \
    glds16(bS0 + (k0), BsW + (so_) * 4096);            \
    glds16(bS1 + (k0), BsW + (so_) * 4096 + 2048);     \
  } while (0)

#define COMPUTE(so_)                                                            \
  do {                                                                          \
    short8 af[4], bv[4];                                                        \
    _Pragma("unroll") for (int i = 0; i < 4; i++)                               \
        af[i] = *reinterpret_cast<const short8*>(                               \
            &As[(so_) * 4096 + (wm * 64 + i * 16 + fr) * 32 + gph]);            \
    _Pragma("unroll") for (int j = 0; j < 4; j++)                               \
        bv[j] = *reinterpret_cast<const short8*>(                               \
            &Bs[(so_) * 4096 + (wn * 64 + j * 16 + fr) * 32 + gph]);            \
    _Pragma("unroll") for (int i = 0; i < 4; i++)                               \
      _Pragma("unroll") for (int j = 0; j < 4; j++)                             \
          acc[i][j] = __builtin_amdgcn_mfma_f32_16x16x32_bf16(af[i], bv[j],     \
                                                              acc[i][j], 0, 0, 0); \
  } while (0)

#define PIPELINE(NKT)                                              \
  do {                                                             \
    STAGE(0, 0);                                                   \
    STAGE(1, 32);                                                  \
    for (int kt = 0; kt <= (NKT)-3; ++kt) {                        \
      int so = kt & 1;                                             \
      asm volatile("s_waitcnt vmcnt(4)" ::: "memory");             \
      __builtin_amdgcn_s_barrier();                                \
      COMPUTE(so);                                                 \
      __builtin_amdgcn_s_barrier();                                \
      STAGE(so, (kt + 2) * 32);                                    \
    }                                                              \
    asm volatile("s_waitcnt vmcnt(4)" ::: "memory");               \
    __builtin_amdgcn_s_barrier();                                  \
    COMPUTE(((NKT)-2) & 1);                                        \
    asm volatile("s_waitcnt vmcnt(0)" ::: "memory");               \
    __builtin_amdgcn_s_barrier();                                  \
    COMPUTE(((NKT)-1) & 1);                                        \
  } while (0)

// Inline per-block meta from cnt: off_e = prefix sum, m_e = ceil(ce/128)
#define EXPERT_META                                    \
  int ce = cnt[e];                                     \
  int off_e = 0;                                       \
  _Pragma("unroll") for (int i_ = 0; i_ < Ee; i_++)    \
      off_e += (i_ < e) ? cnt[i_] : 0;                 \
  int m_e = (ce + 127) >> 7;

// ==== fused: GEMM1 (blocks 0..2047) + W2 cvt (blocks 2048..6143) ====
// gemm1 is latency-bound at ~8% HBM; the W2 conversion (128MB traffic) rides the idle BW.
__global__ __launch_bounds__(256) void gemm1_cvtw2_kernel(
    const unsigned short* __restrict__ xg, const unsigned short* __restrict__ w1b,
    const float* __restrict__ b1,
    const int* __restrict__ cnt,
    unsigned short* __restrict__ hb,
    const float* __restrict__ w2, unsigned short* __restrict__ w2b) {
  const int GB = 2048;   // gemm1 blocks
  __shared__ short As[2 * 4096];
  __shared__ short Bs[2 * 4096];

  if (blockIdx.x >= GB) {
    const int n8 = Ee * Dd * Hh / 8;
    int i = (blockIdx.x - GB) * 256 + threadIdx.x;
    int stride = (gridDim.x - GB) * 256;
    const float4* src = reinterpret_cast<const float4*>(w2);
    uint4* dst = reinterpret_cast<uint4*>(w2b);
    for (; i < n8; i += stride) {
      float4 a = src[2 * i], b = src[2 * i + 1];
      uint4 o;
      o.x = pack2bf(a.x, a.y);
      o.y = pack2bf(a.z, a.w);
      o.z = pack2bf(b.x, b.y);
      o.w = pack2bf(b.z, b.w);
      dst[i] = o;
    }
    return;
  }

  int e = blockIdx.x & 7;
  const int G = GB >> 3;   // 256
  EXPERT_META
  int span = m_e * (Hh / 128);

  int tid = threadIdx.x;
  int lane = tid & 63;
  int w = tid >> 6;
  int wm = w >> 1, wn = w & 1;
  int fr = lane & 15, kq = lane >> 4;

  int r0 = tid >> 2;
  int swz = ((tid & 3) ^ ((r0 >> 1) & 3)) << 3;
  short* AsW = &As[w * 512];
  short* BsW = &Bs[w * 512];
  int gph = (kq ^ ((fr >> 1) & 3)) << 3;
  const float* b1e = b1 + (size_t)e * Hh;

  for (int local = blockIdx.x >> 3; local < span; local += G) {
    int nt = local / m_e, mt = local % m_e;
    __syncthreads();

    const unsigned short* aS0 = xg + (size_t)e * Tt * Dd + (size_t)(mt * 128 + r0) * Dd + swz;
    const unsigned short* aS1 = aS0 + (size_t)64 * Dd;
    const unsigned short* bS0 = w1b + (size_t)e * Hh * Dd + (size_t)(nt * 128 + r0) * Dd + swz;
    const unsigned short* bS1 = bS0 + (size_t)64 * Dd;

    float biasj[4];
#pragma unroll
    for (int j = 0; j < 4; j++) biasj[j] = b1e[nt * 128 + wn * 64 + j * 16 + fr];
    asm volatile("s_waitcnt vmcnt(0)" ::: "memory");

    f32x4 acc[4][4] = {};
    PIPELINE(Dd / 32);

#pragma unroll
    for (int i = 0; i < 4; i++) {
      int rb = wm * 64 + i * 16 + kq * 4;
#pragma unroll
      for (int j = 0; j < 4; j++) {
        int col = nt * 128 + wn * 64 + j * 16 + fr;
#pragma unroll
        for (int rr = 0; rr < 4; rr++) {
          int grow = mt * 128 + rb + rr;
          if (grow < ce) {
            float v = fast_gelu(acc[i][j][rr] + biasj[j]);
            hb[(size_t)(off_e + grow) * Hh + col] = f2bf_bits(v);
          }
        }
      }
    }
  }
}

// ---------------- GEMM2 (r18): y[en] = h @ W2[e]^T + b2[e], plain stores ---------------
__global__ __launch_bounds__(256) void gemm2_kernel(
    const unsigned short* __restrict__ hb, const unsigned short* __restrict__ w2b,
    const float* __restrict__ b2,
    const int* __restrict__ cnt, const int* __restrict__ list,
    float* __restrict__ y) {
  int e = blockIdx.x & 7;
  int G = gridDim.x >> 3;
  EXPERT_META
  int span = m_e * (Dd / 128);

  __shared__ short As[2 * 4096];
  __shared__ short Bs[2 * 4096];

  int tid = threadIdx.x;
  int lane = tid & 63;
  int w = tid >> 6;
  int wm = w >> 1, wn = w & 1;
  int fr = lane & 15, kq = lane >> 4;

  int r0 = tid >> 2;
  int swz = ((tid & 3) ^ ((r0 >> 1) & 3)) << 3;
  short* AsW = &As[w * 512];
  short* BsW = &Bs[w * 512];
  int gph = (kq ^ ((fr >> 1) & 3)) << 3;
  const int* le = list + e * Tt;
  const float* b2e = b2 + (size_t)e * Dd;

  for (int local = blockIdx.x >> 3; local < span; local += G) {
    int nt = local / m_e, mt = local % m_e;
    __syncthreads();

    int ra0 = mt * 128 + r0;      if (ra0 >= ce) ra0 = ce - 1;
    int ra1 = mt * 128 + r0 + 64; if (ra1 >= ce) ra1 = ce - 1;
    const unsigned short* aS0 = hb + (size_t)(off_e + ra0) * Hh + swz;
    const unsigned short* aS1 = hb + (size_t)(off_e + ra1) * Hh + swz;
    const unsigned short* bS0 = w2b + (size_t)e * Dd * Hh + (size_t)(nt * 128 + r0) * Hh + swz;
    const unsigned short* bS1 = bS0 + (size_t)64 * Hh;

    float biasj[4];
#pragma unroll
    for (int j = 0; j < 4; j++) biasj[j] = b2e[nt * 128 + wn * 64 + j * 16 + fr];
    asm volatile("s_waitcnt vmcnt(0)" ::: "memory");

    f32x4 acc[4][4] = {};
    PIPELINE(Hh / 32);   // full K = 4096, 128 steps

#pragma unroll
    for (int i = 0; i < 4; i++) {
      int rb = wm * 64 + i * 16 + kq * 4;
#pragma unroll
      for (int j = 0; j < 4; j++) {
        int col = nt * 128 + wn * 64 + j * 16 + fr;
#pragma unroll
        for (int rr = 0; rr < 4; rr++) {
          int grow = mt * 128 + rb + rr;
          if (grow < ce) {
            int en = le[grow];
            y[(size_t)en * Dd + col] = acc[i][j][rr] + biasj[j];
          }
        }
      }
    }
  }
}

// ---------------- combine: out[t] = g0*y[2t] + g1*y[2t+1] ----------------
__global__ __launch_bounds__(256) void combine_kernel(
    const float* __restrict__ y, const float* __restrict__ g2, float* __restrict__ out) {
  const int C4 = Dd / 4;
  int i = blockIdx.x * blockDim.x + threadIdx.x;
  int t = i / C4;
  int c = i % C4;
  float g0 = g2[t * 2 + 0];
  float g1 = g2[t * 2 + 1];
  float4 y0 = reinterpret_cast<const float4*>(y)[(size_t)(t * 2 + 0) * C4 + c];
  float4 y1 = reinterpret_cast<const float4*>(y)[(size_t)(t * 2 + 1) * C4 + c];
  float4 o;
  o.x = g0 * y0.x + g1 * y1.x;
  o.y = g0 * y0.y + g1 * y1.y;
  o.z = g0 * y0.z + g1 * y1.z;
  o.w = g0 * y0.w + g1 * y1.w;
  reinterpret_cast<float4*>(out)[i] = o;
}

extern "C" void kernel_launch(void* const* d_in, const int* in_sizes, int n_in,
                              void* d_out, int out_size, void* d_ws, size_t ws_size,
                              hipStream_t stream) {
  const float* x  = (const float*)d_in[0];
  const float* Wr = (const float*)d_in[1];
  const float* br = (const float*)d_in[2];
  const float* W1 = (const float*)d_in[3];
  const float* b1 = (const float*)d_in[4];
  const float* W2 = (const float*)d_in[5];
  const float* b2 = (const float*)d_in[6];
  float* out = (float*)d_out;

  char* base = (char*)d_ws;
  size_t o = 0;
  auto alloc = [&](size_t n) { char* r = base + o; o += (n + 255) & ~(size_t)255; return r; };
  unsigned short* w1b = (unsigned short*)alloc((size_t)Ee * Hh * Dd * 2);
  unsigned short* w2b = (unsigned short*)alloc((size_t)Ee * Dd * Hh * 2);
  unsigned short* xg  = (unsigned short*)alloc((size_t)Ee * Tt * Dd * 2);
  unsigned short* hb  = (unsigned short*)alloc((size_t)(Tt * Kk + 256) * Hh * 2);
  int* list  = (int*)alloc((size_t)Ee * Tt * 4);
  float* g2  = (float*)alloc((size_t)Tt * Kk * 4);
  int* tokinfo = (int*)alloc(Tt * 4);
  int* pos   = (int*)alloc((size_t)Tt * Kk * 4);
  int* cnt   = (int*)alloc(Ee * 4);
  if (o > ws_size) return;  // workspace too small: fail loudly (output stays poisoned)

  // w1b (64MB) dead after gemm1; holds y[Tt*Kk][Dd] f32 (32MB).
  float* y = (float*)w1b;

  cvt_router_kernel<<<1024 + 4096, 256, 0, stream>>>(x, Wr, br, W1, w1b, tokinfo, g2);
  assign_kernel<<<1, 256, 0, stream>>>(tokinfo, pos, list, cnt);
  gather_kernel<<<Tt / 4, 256, 0, stream>>>(x, pos, xg);

  gemm1_cvtw2_kernel<<<2048 + 4096, 256, 0, stream>>>(xg, w1b, b1, cnt, hb, W2, w2b);
  gemm2_kernel<<<1024, 256, 0, stream>>>(hb, w2b, b2, cnt, list, y);
  combine_kernel<<<(Tt * Dd / 4) / 256, 256, 0, stream>>>(y, g2, out);
}

// Round 25
// 357.504 us; speedup vs baseline: 1.5086x; 1.0402x over previous
//
#include <hip/hip_runtime.h>
#include <hip/hip_bf16.h>

#define Dd 1024
#define Hh 4096
#define Ee 8
#define Tt 4096   // tokens = 2*2048
#define Kk 2

typedef __attribute__((ext_vector_type(8))) short short8;
typedef __attribute__((ext_vector_type(4))) float f32x4;

__device__ __forceinline__ unsigned short f2bf_bits(float f) {
  unsigned u = __builtin_bit_cast(unsigned, f);
  u += 0x7FFFu + ((u >> 16) & 1u);   // RNE (finite values)
  return (unsigned short)(u >> 16);
}

__device__ __forceinline__ unsigned pack2bf(float lo, float hi) {
  return (unsigned)f2bf_bits(lo) | ((unsigned)f2bf_bits(hi) << 16);
}

// Exact-erf GELU via Abramowitz-Stegun 7.1.26 (max |err(erf)| = 1.5e-7, branch-free).
__device__ __forceinline__ float fast_gelu(float v) {
  float z = v * 0.70710678118654752f;
  float az = fabsf(z);
  float t = __frcp_rn(1.0f + 0.3275911f * az);
  float poly = t * (0.254829592f + t * (-0.284496736f + t * (1.421413741f +
               t * (-1.453152027f + t * 1.061405429f))));
  float e = __expf(-az * az);
  float erf_az = 1.0f - poly * e;
  float erf_z = copysignf(erf_az, z);
  return 0.5f * v * (1.0f + erf_z);
}

__device__ __forceinline__ void glds16(const void* g, void* l) {
  __builtin_amdgcn_global_load_lds(
      (const __attribute__((address_space(1))) unsigned int*)g,
      (__attribute__((address_space(3))) unsigned int*)l, 16, 0, 0);
}

// ======= fused: router + xb write (blocks 0..1023) + W1 cvt (rest) =======
// Router also emits xb = bf16 copy of x in TOKEN order (replaces the gather pass:
// gemm1 now stages A indirectly via per-lane glds source addresses).
__global__ __launch_bounds__(256) void cvt_router_kernel(
    const float* __restrict__ x, const float* __restrict__ Wr, const float* __restrict__ br,
    const float* __restrict__ w1, unsigned short* __restrict__ w1b,
    int* __restrict__ tokinfo, float* __restrict__ g2,
    unsigned short* __restrict__ xb) {
  const int RB = Tt / 4;   // 1024 router blocks
  if (blockIdx.x < RB) {
    int t = blockIdx.x * 4 + (threadIdx.x >> 6);
    int lane = threadIdx.x & 63;
    const float4* x4 = reinterpret_cast<const float4*>(x + (size_t)t * Dd);
    const float4* Wr4 = reinterpret_cast<const float4*>(Wr);
    float pe[Ee];
#pragma unroll
    for (int e = 0; e < Ee; e++) pe[e] = 0.f;
    for (int c = lane; c < Dd / 4; c += 64) {
      float4 xv = x4[c];
#pragma unroll
      for (int e = 0; e < Ee; e++) {
        float4 wv = Wr4[e * (Dd / 4) + c];
        pe[e] += xv.x * wv.x + xv.y * wv.y + xv.z * wv.z + xv.w * wv.w;
      }
    }
    // bf16 token-order copy (x is L1/L2-hot from the dot products)
    uint4* xbr = (uint4*)(xb + (size_t)t * Dd);
#pragma unroll
    for (int it = 0; it < 2; ++it) {
      int c = lane + it * 64;        // 8-elem chunk, 0..127
      float4 a = x4[2 * c], b = x4[2 * c + 1];
      uint4 o;
      o.x = pack2bf(a.x, a.y);
      o.y = pack2bf(a.z, a.w);
      o.z = pack2bf(b.x, b.y);
      o.w = pack2bf(b.z, b.w);
      xbr[c] = o;
    }
#pragma unroll
    for (int e = 0; e < Ee; e++) {
      float v = pe[e];
#pragma unroll
      for (int s = 32; s > 0; s >>= 1) v += __shfl_xor(v, s);
      pe[e] = v + br[e];
    }
    if (lane == 0) {
      float mx = pe[0];
#pragma unroll
      for (int e = 1; e < Ee; e++) mx = fmaxf(mx, pe[e]);
      float g[Ee];
      float sum = 0.f;
#pragma unroll
      for (int e = 0; e < Ee; e++) { g[e] = expf(pe[e] - mx); sum += g[e]; }
      float inv = 1.0f / sum;
      int e0 = 0; float g0v = g[0];
#pragma unroll
      for (int e = 1; e < Ee; e++) if (g[e] > g0v) { g0v = g[e]; e0 = e; }
      int e1 = -1; float g1v = -1.f;
#pragma unroll
      for (int e = 0; e < Ee; e++) if (e != e0 && g[e] > g1v) { g1v = g[e]; e1 = e; }
      g2[t * 2 + 0] = g0v * inv;
      g2[t * 2 + 1] = g1v * inv;
      tokinfo[t] = e0 | (e1 << 8);
    }
  } else {
    const int n8 = Ee * Hh * Dd / 8;
    int i = (blockIdx.x - RB) * 256 + threadIdx.x;
    int stride = (gridDim.x - RB) * 256;
    const float4* src = reinterpret_cast<const float4*>(w1);
    uint4* dst = reinterpret_cast<uint4*>(w1b);
    for (; i < n8; i += stride) {
      float4 a = src[2 * i], b = src[2 * i + 1];
      uint4 o;
      o.x = pack2bf(a.x, a.y);
      o.y = pack2bf(a.z, a.w);
      o.z = pack2bf(b.x, b.y);
      o.w = pack2bf(b.z, b.w);
      dst[i] = o;
    }
  }
}

// ---------------- assign: LDS counters -> list, cnt (1 block) ----------------
__global__ void assign_kernel(const int* __restrict__ tokinfo,
                              int* __restrict__ list, int* __restrict__ cnt) {
  __shared__ int lc[Ee];
  int tid = threadIdx.x;
  if (tid < Ee) lc[tid] = 0;
  __syncthreads();
  for (int t = tid; t < Tt; t += 256) {
    int info = tokinfo[t];
    int e0 = info & 255, e1 = info >> 8;
    int p0 = atomicAdd(&lc[e0], 1);
    list[e0 * Tt + p0] = t * 2;
    int p1 = atomicAdd(&lc[e1], 1);
    list[e1 * Tt + p1] = t * 2 + 1;
  }
  __syncthreads();
  if (tid < Ee) cnt[tid] = lc[tid];
}

// ================== 128x128 tile, BK=32, 4 waves (2x2) — r12/r14/r18-proven ==============
#define STAGE(so_, k0)                                 \
  do {                                                 \
    glds16(aS0 + (k0), AsW + (so_) * 4096);            \
    glds16(aS1 + (k0), AsW + (so_) * 4096 + 2048);     \
    glds16(bS0 + (k0), BsW + (so_) * 4096);            \
    glds16(bS1 + (k0), BsW + (so_) * 4096 + 2048);     \
  } while (0)

#define COMPUTE(so_)                                                            \
  do {                                                                          \
    short8 af[4], bv[4];                                                        \
    _Pragma("unroll") for (int i = 0; i < 4; i++)                               \
        af[i] = *reinterpret_cast<const short8*>(                               \
            &As[(so_) * 4096 + (wm * 64 + i * 16 + fr) * 32 + gph]);            \
    _Pragma("unroll") for (int j = 0; j < 4; j++)                               \
        bv[j] = *reinterpret_cast<const short8*>(                               \
            &Bs[(so_) * 4096 + (wn * 64 + j * 16 + fr) * 32 + gph]);            \
    _Pragma("unroll") for (int i = 0; i < 4; i++)                               \
      _Pragma("unroll") for (int j = 0; j < 4; j++)                             \
          acc[i][j] = __builtin_amdgcn_mfma_f32_16x16x32_bf16(af[i], bv[j],     \
                                                              acc[i][j], 0, 0, 0); \
  } while (0)

#define PIPELINE(NKT)                                              \
  do {                                                             \
    STAGE(0, 0);                                                   \
    STAGE(1, 32);                                                  \
    for (int kt = 0; kt <= (NKT)-3; ++kt) {                        \
      int so = kt & 1;                                             \
      asm volatile("s_waitcnt vmcnt(4)" ::: "memory");             \
      __builtin_amdgcn_s_barrier();                                \
      COMPUTE(so);                                                 \
      __builtin_amdgcn_s_barrier();                                \
      STAGE(so, (kt + 2) * 32);                                    \
    }                                                              \
    asm volatile("s_waitcnt vmcnt(4)" ::: "memory");               \
    __builtin_amdgcn_s_barrier();                                  \
    COMPUTE(((NKT)-2) & 1);                                        \
    asm volatile("s_waitcnt vmcnt(0)" ::: "memory");               \
    __builtin_amdgcn_s_barrier();                                  \
    COMPUTE(((NKT)-1) & 1);                                        \
  } while (0)

// Inline per-block meta from cnt: off_e = prefix sum, m_e = ceil(ce/128)
#define EXPERT_META                                    \
  int ce = cnt[e];                                     \
  int off_e = 0;                                       \
  _Pragma("unroll") for (int i_ = 0; i_ < Ee; i_++)    \
      off_e += (i_ < e) ? cnt[i_] : 0;                 \
  int m_e = (ce + 127) >> 7;

// ==== fused: GEMM1 indirect-A (blocks 0..2047) + W2 cvt (blocks 2048..6143) ====
// A staged straight from token-order xb via per-lane glds source addresses (list-indexed);
// coalescing identical to the gathered version (16 x 64B full segments per glds).
__global__ __launch_bounds__(256) void gemm1_cvtw2_kernel(
    const unsigned short* __restrict__ xb, const unsigned short* __restrict__ w1b,
    const float* __restrict__ b1,
    const int* __restrict__ cnt, const int* __restrict__ list,
    unsigned short* __restrict__ hb,
    const float* __restrict__ w2, unsigned short* __restrict__ w2b) {
  const int GB = 2048;   // gemm1 blocks
  __shared__ short As[2 * 4096];
  __shared__ short Bs[2 * 4096];

  if (blockIdx.x >= GB) {
    const int n8 = Ee * Dd * Hh / 8;
    int i = (blockIdx.x - GB) * 256 + threadIdx.x;
    int stride = (gridDim.x - GB) * 256;
    const float4* src = reinterpret_cast<const float4*>(w2);
    uint4* dst = reinterpret_cast<uint4*>(w2b);
    for (; i < n8; i += stride) {
      float4 a = src[2 * i], b = src[2 * i + 1];
      uint4 o;
      o.x = pack2bf(a.x, a.y);
      o.y = pack2bf(a.z, a.w);
      o.z = pack2bf(b.x, b.y);
      o.w = pack2bf(b.z, b.w);
      dst[i] = o;
    }
    return;
  }

  int e = blockIdx.x & 7;
  const int G = GB >> 3;   // 256
  EXPERT_META
  int span = m_e * (Hh / 128);

  int tid = threadIdx.x;
  int lane = tid & 63;
  int w = tid >> 6;
  int wm = w >> 1, wn = w & 1;
  int fr = lane & 15, kq = lane >> 4;

  int r0 = tid >> 2;
  int swz = ((tid & 3) ^ ((r0 >> 1) & 3)) << 3;
  short* AsW = &As[w * 512];
  short* BsW = &Bs[w * 512];
  int gph = (kq ^ ((fr >> 1) & 3)) << 3;
  const float* b1e = b1 + (size_t)e * Hh;
  const int* le = list + e * Tt;

  for (int local = blockIdx.x >> 3; local < span; local += G) {
    int nt = local / m_e, mt = local % m_e;
    __syncthreads();

    // Indirect A row pointers (clamped); loaded with biasj, drained before PIPELINE
    // so the counted vmcnt stays exact.
    int ga0 = mt * 128 + r0;      if (ga0 >= ce) ga0 = ce - 1;
    int ga1 = mt * 128 + r0 + 64; if (ga1 >= ce) ga1 = ce - 1;
    int tok0 = le[ga0] >> 1;
    int tok1 = le[ga1] >> 1;
    const unsigned short* aS0 = xb + (size_t)tok0 * Dd + swz;
    const unsigned short* aS1 = xb + (size_t)tok1 * Dd + swz;
    const unsigned short* bS0 = w1b + (size_t)e * Hh * Dd + (size_t)(nt * 128 + r0) * Dd + swz;
    const unsigned short* bS1 = bS0 + (size_t)64 * Dd;

    float biasj[4];
#pragma unroll
    for (int j = 0; j < 4; j++) biasj[j] = b1e[nt * 128 + wn * 64 + j * 16 + fr];
    asm volatile("s_waitcnt vmcnt(0)" ::: "memory");

    f32x4 acc[4][4] = {};
    PIPELINE(Dd / 32);

#pragma unroll
    for (int i = 0; i < 4; i++) {
      int rb = wm * 64 + i * 16 + kq * 4;
#pragma unroll
      for (int j = 0; j < 4; j++) {
        int col = nt * 128 + wn * 64 + j * 16 + fr;
#pragma unroll
        for (int rr = 0; rr < 4; rr++) {
          int grow = mt * 128 + rb + rr;
          if (grow < ce) {
            float v = fast_gelu(acc[i][j][rr] + biasj[j]);
            hb[(size_t)(off_e + grow) * Hh + col] = f2bf_bits(v);
          }
        }
      }
    }
  }
}

// ---------------- GEMM2 (r18): y[en] = h @ W2[e]^T + b2[e], plain stores ---------------
__global__ __launch_bounds__(256) void gemm2_kernel(
    const unsigned short* __restrict__ hb, const unsigned short* __restrict__ w2b,
    const float* __restrict__ b2,
    const int* __restrict__ cnt, const int* __restrict__ list,
    float* __restrict__ y) {
  int e = blockIdx.x & 7;
  int G = gridDim.x >> 3;
  EXPERT_META
  int span = m_e * (Dd / 128);

  __shared__ short As[2 * 4096];
  __shared__ short Bs[2 * 4096];

  int tid = threadIdx.x;
  int lane = tid & 63;
  int w = tid >> 6;
  int wm = w >> 1, wn = w & 1;
  int fr = lane & 15, kq = lane >> 4;

  int r0 = tid >> 2;
  int swz = ((tid & 3) ^ ((r0 >> 1) & 3)) << 3;
  short* AsW = &As[w * 512];
  short* BsW = &Bs[w * 512];
  int gph = (kq ^ ((fr >> 1) & 3)) << 3;
  const int* le = list + e * Tt;
  const float* b2e = b2 + (size_t)e * Dd;

  for (int local = blockIdx.x >> 3; local < span; local += G) {
    int nt = local / m_e, mt = local % m_e;
    __syncthreads();

    int ra0 = mt * 128 + r0;      if (ra0 >= ce) ra0 = ce - 1;
    int ra1 = mt * 128 + r0 + 64; if (ra1 >= ce) ra1 = ce - 1;
    const unsigned short* aS0 = hb + (size_t)(off_e + ra0) * Hh + swz;
    const unsigned short* aS1 = hb + (size_t)(off_e + ra1) * Hh + swz;
    const unsigned short* bS0 = w2b + (size_t)e * Dd * Hh + (size_t)(nt * 128 + r0) * Hh + swz;
    const unsigned short* bS1 = bS0 + (size_t)64 * Hh;

    float biasj[4];
#pragma unroll
    for (int j = 0; j < 4; j++) biasj[j] = b2e[nt * 128 + wn * 64 + j * 16 + fr];
    asm volatile("s_waitcnt vmcnt(0)" ::: "memory");

    f32x4 acc[4][4] = {};
    PIPELINE(Hh / 32);   // full K = 4096, 128 steps

#pragma unroll
    for (int i = 0; i < 4; i++) {
      int rb = wm * 64 + i * 16 + kq * 4;
#pragma unroll
      for (int j = 0; j < 4; j++) {
        int col = nt * 128 + wn * 64 + j * 16 + fr;
#pragma unroll
        for (int rr = 0; rr < 4; rr++) {
          int grow = mt * 128 + rb + rr;
          if (grow < ce) {
            int en = le[grow];
            y[(size_t)en * Dd + col] = acc[i][j][rr] + biasj[j];
          }
        }
      }
    }
  }
}

// ---------------- combine: out[t] = g0*y[2t] + g1*y[2t+1] ----------------
__global__ __launch_bounds__(256) void combine_kernel(
    const float* __restrict__ y, const float* __restrict__ g2, float* __restrict__ out) {
  const int C4 = Dd / 4;
  int i = blockIdx.x * blockDim.x + threadIdx.x;
  int t = i / C4;
  int c = i % C4;
  float g0 = g2[t * 2 + 0];
  float g1 = g2[t * 2 + 1];
  float4 y0 = reinterpret_cast<const float4*>(y)[(size_t)(t * 2 + 0) * C4 + c];
  float4 y1 = reinterpret_cast<const float4*>(y)[(size_t)(t * 2 + 1) * C4 + c];
  float4 o;
  o.x = g0 * y0.x + g1 * y1.x;
  o.y = g0 * y0.y + g1 * y1.y;
  o.z = g0 * y0.z + g1 * y1.z;
  o.w = g0 * y0.w + g1 * y1.w;
  reinterpret_cast<float4*>(out)[i] = o;
}

extern "C" void kernel_launch(void* const* d_in, const int* in_sizes, int n_in,
                              void* d_out, int out_size, void* d_ws, size_t ws_size,
                              hipStream_t stream) {
  const float* x  = (const float*)d_in[0];
  const float* Wr = (const float*)d_in[1];
  const float* br = (const float*)d_in[2];
  const float* W1 = (const float*)d_in[3];
  const float* b1 = (const float*)d_in[4];
  const float* W2 = (const float*)d_in[5];
  const float* b2 = (const float*)d_in[6];
  float* out = (float*)d_out;

  char* base = (char*)d_ws;
  size_t o = 0;
  auto alloc = [&](size_t n) { char* r = base + o; o += (n + 255) & ~(size_t)255; return r; };
  unsigned short* w1b = (unsigned short*)alloc((size_t)Ee * Hh * Dd * 2);
  unsigned short* w2b = (unsigned short*)alloc((size_t)Ee * Dd * Hh * 2);
  unsigned short* xb  = (unsigned short*)alloc((size_t)Tt * Dd * 2);
  unsigned short* hb  = (unsigned short*)alloc((size_t)(Tt * Kk + 256) * Hh * 2);
  int* list  = (int*)alloc((size_t)Ee * Tt * 4);
  float* g2  = (float*)alloc((size_t)Tt * Kk * 4);
  int* tokinfo = (int*)alloc(Tt * 4);
  int* cnt   = (int*)alloc(Ee * 4);
  if (o > ws_size) return;  // workspace too small: fail loudly (output stays poisoned)

  // w1b (64MB) dead after gemm1; holds y[Tt*Kk][Dd] f32 (32MB).
  float* y = (float*)w1b;

  cvt_router_kernel<<<1024 + 4096, 256, 0, stream>>>(x, Wr, br, W1, w1b, tokinfo, g2, xb);
  assign_kernel<<<1, 256, 0, stream>>>(tokinfo, list, cnt);

  gemm1_cvtw2_kernel<<<2048 + 4096, 256, 0, stream>>>(xb, w1b, b1, cnt, list, hb, W2, w2b);
  gemm2_kernel<<<512, 256, 0, stream>>>(hb, w2b, b2, cnt, list, y);
  combine_kernel<<<(Tt * Dd / 4) / 256, 256, 0, stream>>>(y, g2, out);
}